// Round 1
// baseline (1327.743 us; speedup 1.0000x reference)
//
#include <hip/hip_runtime.h>
#include <math.h>

#define U_ 8192
#define I_ 8192
#define D_ 128
#define E_ 524288
#define N_ 16384
#define K_ 32
#define CAP_ 512

typedef unsigned short u16;
typedef unsigned int u32;
typedef unsigned long long u64;
typedef __attribute__((ext_vector_type(8))) short bf16x8;
typedef __attribute__((ext_vector_type(4))) float f32x4;

// ---------------------------------------------------------------- init ------
__global__ void k_init(const float* __restrict__ wq, const float* __restrict__ wk,
                       const float* __restrict__ bq, const float* __restrict__ wv,
                       float* __restrict__ M, float* __restrict__ bqk,
                       float* __restrict__ wvT,
                       int* __restrict__ cnt, float* __restrict__ cs1,
                       float* __restrict__ cs2, float* __restrict__ C2,
                       float* __restrict__ svec, int* __restrict__ gcount,
                       int* __restrict__ failn) {
  const int tid = blockIdx.x * 256 + threadIdx.x;   // 64 blocks -> 16384 threads
  cnt[tid] = 0;
  gcount[tid] = 0;
  C2[tid] = 0.f;
  if (tid < 128) { cs1[tid] = 0.f; cs2[tid] = 0.f; svec[tid] = 0.f; }
  if (tid == 0) *failn = 0;
  // M[i][j] = sum_l wq[l,i]*wk[l,j]  (wq^T wk)
  const int i = tid >> 7, j = tid & 127;
  float s = 0.f;
  for (int l = 0; l < 128; ++l) s += wq[l * 128 + i] * wk[l * 128 + j];
  M[tid] = s;
  wvT[i * 128 + j] = wv[j * 128 + i];
  if (tid < 128) {
    float s2 = 0.f;
    for (int l = 0; l < 128; ++l) s2 += bq[l] * wk[l * 128 + tid];
    bqk[tid] = s2;
  }
}

__global__ void k_concat(const float* __restrict__ user, const float* __restrict__ item,
                         float* __restrict__ ego) {
  const int i = blockIdx.x * 256 + threadIdx.x;     // 8192 blocks, exact
  ego[i] = (i < U_ * D_) ? user[i] : item[i - U_ * D_];
}

// ---------------------------------------------------------------- CSR -------
__global__ void k_hist(const int* __restrict__ rows, int* __restrict__ cnt) {
  const int e = blockIdx.x * 256 + threadIdx.x;     // 2048 blocks, exact
  atomicAdd(&cnt[rows[e]], 1);
}

__global__ void k_scan(const int* __restrict__ cnt, int* __restrict__ row_ptr,
                       int* __restrict__ cursor) {
  __shared__ int buf[1024];
  __shared__ int carry;
  const int t = threadIdx.x;
  if (t == 0) carry = 0;
  __syncthreads();
  for (int c = 0; c < N_ / 1024; ++c) {
    const int x = cnt[c * 1024 + t];
    buf[t] = x;
    __syncthreads();
    for (int off = 1; off < 1024; off <<= 1) {
      int v = (t >= off) ? buf[t - off] : 0;
      __syncthreads();
      buf[t] += v;
      __syncthreads();
    }
    const int incl = buf[t];
    const int excl = carry + incl - x;
    row_ptr[c * 1024 + t] = excl;
    cursor[c * 1024 + t] = excl;
    __syncthreads();
    if (t == 1023) carry += incl;
    __syncthreads();
  }
  if (t == 0) row_ptr[N_] = carry;
}

__global__ void k_scatter(const int* __restrict__ rows, const int* __restrict__ cols,
                          const float* __restrict__ vals, int* __restrict__ cursor,
                          int* __restrict__ ccol, float* __restrict__ cval) {
  const int e = blockIdx.x * 256 + threadIdx.x;
  const int r = rows[e];
  const int p = atomicAdd(&cursor[r], 1);
  ccol[p] = cols[e];
  cval[p] = vals[e];
}

// ---------------------------------------------------------------- SpMM ------
__global__ __launch_bounds__(128) void k_spmm(const float* __restrict__ x,
                                              float* __restrict__ y,
                                              float* __restrict__ sum,
                                              const int* __restrict__ row_ptr,
                                              const int* __restrict__ ccol,
                                              const float* __restrict__ cval,
                                              const int first) {
  const int r = blockIdx.x, d = threadIdx.x;
  const int b = row_ptr[r], e = row_ptr[r + 1];
  double acc = 0.0;
  for (int i = b; i < e; ++i)
    acc += (double)cval[i] * (double)x[ccol[i] * 128 + d];
  const float f = (float)acc;
  y[r * 128 + d] = f;
  if (first) sum[r * 128 + d] = f; else sum[r * 128 + d] += f;
}

__global__ void k_div3(float* __restrict__ a) {
  const int i = blockIdx.x * 256 + threadIdx.x;
  a[i] = a[i] / 3.0f;
}

// ------------------------------------------------- split + transpose --------
__global__ __launch_bounds__(256) void k_split_t(const float* __restrict__ x,
                                                 u16* __restrict__ Gh, u16* __restrict__ Gl,
                                                 u16* __restrict__ XTh, u16* __restrict__ XTl,
                                                 float* __restrict__ svec) {
  __shared__ u16 lh[128 * 66];
  __shared__ u16 ll[128 * 66];
  const int tid = threadIdx.x;
  const int r0 = blockIdx.x * 64;
  float colsum = 0.f;
  for (int s = 0; s < 32; ++s) {
    const int idx = tid + s * 256;
    const int r = idx >> 7, d = idx & 127;
    const float v = x[(r0 + r) * 128 + d];
    colsum += v;
    unsigned int u = __float_as_uint(v);
    u += 0x7fffu + ((u >> 16) & 1u);
    const u16 h = (u16)(u >> 16);
    const float hf = __uint_as_float(((unsigned int)h) << 16);
    const float l = v - hf;
    unsigned int u2 = __float_as_uint(l);
    u2 += 0x7fffu + ((u2 >> 16) & 1u);
    const u16 lo = (u16)(u2 >> 16);
    Gh[(r0 + r) * 128 + d] = h;
    Gl[(r0 + r) * 128 + d] = lo;
    lh[d * 66 + r] = h;
    ll[d * 66 + r] = lo;
  }
  atomicAdd(&svec[tid & 127], colsum);
  __syncthreads();
  for (int s = 0; s < 32; ++s) {
    const int idx = tid + s * 256;
    const int d = idx >> 6, rr = idx & 63;
    XTh[d * 16384 + r0 + rr] = lh[d * 66 + rr];
    XTl[d * 16384 + r0 + rr] = ll[d * 66 + rr];
  }
}

// ---------------------------------------------------------------- C2 --------
__global__ __launch_bounds__(256) void k_c2mfma(const u16* __restrict__ XTh,
                                                const u16* __restrict__ XTl,
                                                float* __restrict__ C2) {
  const int tid = threadIdx.x, w = tid >> 6, lane = tid & 63;
  const int n16 = lane & 15, kq = lane >> 4;
  const int c0 = blockIdx.x * 512;
  f32x4 acc[2][8];
#pragma unroll
  for (int a = 0; a < 2; ++a)
#pragma unroll
    for (int b = 0; b < 8; ++b) acc[a][b] = (f32x4){0.f, 0.f, 0.f, 0.f};
  for (int ks = 0; ks < 16; ++ks) {
    const int c = c0 + ks * 32 + kq * 8;
    bf16x8 Fh[8], Fl[8];
#pragma unroll
    for (int g = 0; g < 8; ++g) {
      const int base = (g * 16 + n16) * 16384 + c;
      Fh[g] = *(const bf16x8*)&XTh[base];
      Fl[g] = *(const bf16x8*)&XTl[base];
    }
#pragma unroll
    for (int a = 0; a < 2; ++a) {
      const int tr = w * 2 + a;
#pragma unroll
      for (int b = 0; b < 8; ++b) {
        acc[a][b] = __builtin_amdgcn_mfma_f32_16x16x32_bf16(Fl[tr], Fh[b], acc[a][b], 0, 0, 0);
        acc[a][b] = __builtin_amdgcn_mfma_f32_16x16x32_bf16(Fh[tr], Fl[b], acc[a][b], 0, 0, 0);
        acc[a][b] = __builtin_amdgcn_mfma_f32_16x16x32_bf16(Fh[tr], Fh[b], acc[a][b], 0, 0, 0);
      }
    }
  }
#pragma unroll
  for (int a = 0; a < 2; ++a) {
    const int tr = w * 2 + a;
#pragma unroll
    for (int b = 0; b < 8; ++b)
#pragma unroll
      for (int i = 0; i < 4; ++i)
        atomicAdd(&C2[(tr * 16 + kq * 4 + i) * 128 + b * 16 + n16], acc[a][b][i]);
  }
}

// tau_r = mean_r + 2.55 * sigma_r. Containment is STRUCTURAL: count>=36
// guarantees the top-32 (by our scores) all exceed tau; tau only trades
// candidate volume vs fallback frequency.
__global__ __launch_bounds__(128) void k_tau(const float* __restrict__ x,
                                             const float* __restrict__ C2,
                                             const float* __restrict__ svec,
                                             float* __restrict__ tau) {
  __shared__ float xs[128];
  __shared__ double red[128];
  const int n = blockIdx.x, tid = threadIdx.x;
  xs[tid] = x[n * 128 + tid];
  __syncthreads();
  double y = 0.0;
  for (int k2 = 0; k2 < 128; ++k2) y += (double)xs[k2] * (double)C2[k2 * 128 + tid];
  red[tid] = (double)xs[tid] * y;
  __syncthreads();
  for (int s = 64; s; s >>= 1) { if (tid < s) red[tid] += red[tid + s]; __syncthreads(); }
  const double exy = red[0] / 16384.0;
  __syncthreads();
  red[tid] = (double)xs[tid] * (double)svec[tid];
  __syncthreads();
  for (int s = 64; s; s >>= 1) { if (tid < s) red[tid] += red[tid + s]; __syncthreads(); }
  if (tid == 0) {
    const double m = red[0] / 16384.0;
    double var = exy - m * m;
    if (var < 0.0) var = 0.0;
    tau[n] = (float)(m + 2.55 * sqrt(var));
  }
}

// ---------------------------------------------------------------- qk --------
__global__ __launch_bounds__(128) void k_qk(const float* __restrict__ ego,
                                            const float* __restrict__ M,
                                            const float* __restrict__ bqk,
                                            float* __restrict__ qkout) {
  __shared__ float Ml[128 * 128];
  __shared__ float xr[128];
  const int tid = threadIdx.x;
  for (int e = tid; e < 16384; e += 128) Ml[e] = M[e];
  const float bj = bqk[tid];
  for (int r = blockIdx.x; r < N_; r += gridDim.x) {
    __syncthreads();
    xr[tid] = ego[r * 128 + tid];
    __syncthreads();
    float a = bj;
    for (int d = 0; d < 128; ++d) a += xr[d] * Ml[d * 128 + tid];
    qkout[r * 128 + tid] = a;
  }
}

// ------------------------------------------------------- sim via MFMA -------
// TRIANGULAR version: sim is symmetric, and only the top-32 SET per row
// matters (attention is permutation-invariant over samples), so each pair
// (r,c), c>=r is computed ONCE and scattered to both rows.  Tile space is
// upper-triangular: 1088 blocks instead of 2048 (strict-upper tiles
// double-scatter unconditionally; the 128 diagonal blocks skip fully
// sub-diagonal 64-col subtiles and per-element guard the two crossing ones).
// Stored value for row c at col r is hi_c.(hi+lo)_r vs previous
// hi_r.(hi+lo)_c: ~1e-10 asymmetry, same scale as the accepted A-lo-drop
// error, far under the tau containment margin; gcount semantics unchanged.
// Staging now uses global_load_lds (width 16) with pre-swizzled SOURCE
// chunks (LDS stays linear 256B rows); reads XOR the same (row&7) swizzle,
// so ds_read_b128 lanes hit distinct 16B bank slots per 8-lane group.
__device__ __forceinline__ void gload_lds16(const u16* g, u16* l) {
  __builtin_amdgcn_global_load_lds(
      (const __attribute__((address_space(1))) void*)g,
      (__attribute__((address_space(3))) void*)l, 16, 0, 0);
}

__global__ __launch_bounds__(256) void k_simmfma(const u16* __restrict__ Gh,
                                                 const u16* __restrict__ Gl,
                                                 const float* __restrict__ tau,
                                                 int* __restrict__ gcount,
                                                 int2* __restrict__ gbuf) {
  __shared__ __align__(16) u16 lh[64 * 128];   // 16 KB, linear 256-B rows
  const int tid = threadIdx.x;
  const int w = tid >> 6, lane = tid & 63;
  const int n16 = lane & 15, kq = lane >> 4;

  // triangular tile mapping: blocks cover (rgrp, strip) with strip >= rgrp>>3
  int bid = blockIdx.x;
  int g = 0;
  while (bid >= 8 * (16 - g)) { bid -= 8 * (16 - g); ++g; }
  const int rgrp = g * 8 + bid / (16 - g);
  const int strip = g + bid % (16 - g);
  const int diag = (strip == g);
  const int d0 = diag ? ((rgrp & 7) * 2) : -2;   // first col-subtile touching the band

  const int rowbase = rgrp * 128 + w * 32;
  bf16x8 Bh[2][4], Bl[2][4];
#pragma unroll
  for (int rg = 0; rg < 2; ++rg) {
    const int row = rowbase + rg * 16 + n16;
#pragma unroll
    for (int q = 0; q < 4; ++q) {
      Bh[rg][q] = *(const bf16x8*)&Gh[row * 128 + q * 32 + kq * 8];
      Bl[rg][q] = *(const bf16x8*)&Gl[row * 128 + q * 32 + kq * 8];
    }
  }
  const float tau0 = tau[rowbase + n16];
  const float tau1 = tau[rowbase + 16 + n16];
  const int col0 = strip * 1024;

  const int st0 = diag ? d0 : 0;
  for (int st = st0; st < 16; ++st) {
    const int cb = col0 + st * 64;
    __syncthreads();
    // stage 64 rows x 256 B: each wave DMAs 4 rows per issue (1024 B),
    // source chunk pre-swizzled so the read-side XOR finds linear data.
#pragma unroll
    for (int ii = 0; ii < 4; ++ii) {
      const int row = w * 16 + ii * 4 + kq;          // kq = lane>>4 here: 4 rows/issue
      const int chunk = n16 ^ (row & 7);             // 16B chunk within the row
      gload_lds16(Gh + (((size_t)(cb + row)) << 7) + chunk * 8,
                  lh + ((w * 16 + ii * 4) << 7));
    }
    __syncthreads();
    const bool cross = (st <= d0 + 1);               // only true in diagonal blocks
#pragma unroll
    for (int ct = 0; ct < 4; ++ct) {
      const int ar = ct * 16 + n16;
      const char* lbase = (const char*)lh + ar * 256;
      bf16x8 Ah[4];
#pragma unroll
      for (int q = 0; q < 4; ++q)
        Ah[q] = *(const bf16x8*)(lbase + ((q * 64 + kq * 16) ^ ((ar & 7) << 4)));
      const f32x4 tc = *(const f32x4*)&tau[cb + ct * 16 + kq * 4];
#pragma unroll
      for (int rg = 0; rg < 2; ++rg) {
        f32x4 p = {0.f, 0.f, 0.f, 0.f};
        f32x4 r = {0.f, 0.f, 0.f, 0.f};
#pragma unroll
        for (int q = 0; q < 4; ++q) {
          p = __builtin_amdgcn_mfma_f32_16x16x32_bf16(Ah[q], Bh[rg][q], p, 0, 0, 0);
          r = __builtin_amdgcn_mfma_f32_16x16x32_bf16(Ah[q], Bl[rg][q], r, 0, 0, 0);
        }
        const float tv = rg ? tau1 : tau0;
        const int rrow = rowbase + rg * 16 + n16;
        if (!cross) {
          // strictly above the diagonal: c > rrow for every element
#pragma unroll
          for (int i = 0; i < 4; ++i) {
            const float v = p[i] + r[i];
            const int c = cb + ct * 16 + kq * 4 + i;
            if (v > tv) {
              const int pos = atomicAdd(&gcount[rrow], 1);
              if (pos < CAP_) gbuf[rrow * CAP_ + pos] = make_int2(c, __float_as_int(v));
            }
            if (v > tc[i]) {
              const int pos = atomicAdd(&gcount[c], 1);
              if (pos < CAP_) gbuf[c * CAP_ + pos] = make_int2(rrow, __float_as_int(v));
            }
          }
        } else {
          // diagonal-crossing subtile: keep only c >= rrow (pair computed once)
#pragma unroll
          for (int i = 0; i < 4; ++i) {
            const int c = cb + ct * 16 + kq * 4 + i;
            if (c < rrow) continue;
            const float v = p[i] + r[i];
            if (v > tv) {
              const int pos = atomicAdd(&gcount[rrow], 1);
              if (pos < CAP_) gbuf[rrow * CAP_ + pos] = make_int2(c, __float_as_int(v));
            }
            if (c > rrow && v > tc[i]) {
              const int pos = atomicAdd(&gcount[c], 1);
              if (pos < CAP_) gbuf[c * CAP_ + pos] = make_int2(rrow, __float_as_int(v));
            }
          }
        }
      }
    }
  }
}

// rows whose candidate count violates [36,CAP_] go to the exact fallback
__global__ void k_check(const int* __restrict__ gcount, int* __restrict__ failq,
                        int* __restrict__ failn) {
  const int n = blockIdx.x * 256 + threadIdx.x;   // 64 blocks
  const int c = gcount[n];
  if (c < 36 || c > CAP_) {
    const int s = atomicAdd(failn, 1);
    if (s < 64) failq[s] = n;
  }
}

// Top-32 by stored fp32 sim values via RANK-SCATTER on packed u64 keys:
// key = (sortable_f32 << 32) | (16383 - col)  -> (val desc, col asc) order.
// rank = #{keys greater}; rank<32 scatters directly. One wave per row.
__global__ __launch_bounds__(256) void k_refine(const int* __restrict__ gcount,
                                                const int2* __restrict__ gbuf,
                                                int* __restrict__ topk_idx) {
  __shared__ u64 lk[4][CAP_];
  const int tid = threadIdx.x, w = tid >> 6, lane = tid & 63;
  const int n = blockIdx.x * 4 + w;
  const int craw = gcount[n];
  const int bad = (craw < 36 || craw > CAP_);
  const int cnt = bad ? 0 : craw;

  u64 ku[CAP_ / 64];
  int kc[CAP_ / 64];
#pragma unroll
  for (int s = 0; s < CAP_ / 64; ++s) {
    ku[s] = 0; kc[s] = 0;
    const int ci = lane + s * 64;
    if (ci < cnt) {
      const int2 p = gbuf[n * CAP_ + ci];
      u32 uv = (u32)p.y;
      uv = (uv >> 31) ? ~uv : (uv | 0x80000000u);
      const u64 key = ((u64)uv << 32) | (u64)(16383 - p.x);
      lk[w][ci] = key;
      ku[s] = key;
      kc[s] = p.x;
    }
  }
  __syncthreads();

#pragma unroll
  for (int s = 0; s < CAP_ / 64; ++s) {
    const int ci = lane + s * 64;
    if (ci < cnt) {
      const u64 kk = ku[s];
      int r = 0;
#pragma unroll 4
      for (int j = 0; j < cnt; ++j)
        r += (lk[w][j] > kk) ? 1 : 0;
      if (r < 32) topk_idx[n * 32 + r] = kc[s];
    }
  }
  if (bad && lane < 32) topk_idx[n * 32 + lane] = 0;  // placeholder; fallback overwrites
}

// exact fp64 full-row top-32 for statistically-failed rows (expected: none)
__global__ __launch_bounds__(256) void k_fallback(const float* __restrict__ x,
                                                  const int* __restrict__ failq,
                                                  const int* __restrict__ failn,
                                                  double* __restrict__ fsim,
                                                  int* __restrict__ topk_idx) {
  const int nf = *failn;
  const int which = blockIdx.x;
  if (which >= nf || which >= 64) return;
  const int row = failq[which];
  __shared__ float xs[128];
  __shared__ double bm[256];
  __shared__ int bc[256];
  const int tid = threadIdx.x;
  if (tid < 128) xs[tid] = x[row * 128 + tid];
  __syncthreads();
  double* fs = fsim + (size_t)which * 16384;
  for (int c = tid; c < 16384; c += 256) {
    const float4* xp = (const float4*)&x[c * 128];
    double a = 0.0;
    for (int d = 0; d < 32; ++d) {
      const float4 v = xp[d];
      a += (double)xs[d * 4 + 0] * (double)v.x + (double)xs[d * 4 + 1] * (double)v.y +
           (double)xs[d * 4 + 2] * (double)v.z + (double)xs[d * 4 + 3] * (double)v.w;
    }
    fs[c] = a;
  }
  __syncthreads();
  for (int r = 0; r < 32; ++r) {
    double m = -1.0e300; int mc = 0;
    for (int c = tid; c < 16384; c += 256) {
      const double v = fs[c];
      if (v > m || (v == m && c < mc)) { m = v; mc = c; }
    }
    bm[tid] = m; bc[tid] = mc;
    __syncthreads();
    for (int s = 128; s; s >>= 1) {
      if (tid < s) {
        if (bm[tid + s] > bm[tid] || (bm[tid + s] == bm[tid] && bc[tid + s] < bc[tid])) {
          bm[tid] = bm[tid + s]; bc[tid] = bc[tid + s];
        }
      }
      __syncthreads();
    }
    if (tid == 0) { topk_idx[row * 32 + r] = bc[0]; fs[bc[0]] = -1.0e300; }
    __syncthreads();
  }
}

// ------------------------------------------------------- attention ----------
__global__ __launch_bounds__(128) void k_attn(const float* __restrict__ ego,
                                              const float* __restrict__ qk,
                                              const int* __restrict__ topk_idx,
                                              const float* __restrict__ wvT,
                                              const float* __restrict__ bv,
                                              float* __restrict__ atten) {
  __shared__ float qv[128];
  __shared__ float sm[32 * 129];
  __shared__ int tki[32];
  __shared__ float sc[32];
  __shared__ float sa[128];
  __shared__ float psum[128];
  const int n = blockIdx.x, tid = threadIdx.x;
  qv[tid] = qk[n * 128 + tid];
  if (tid < 32) tki[tid] = topk_idx[n * 32 + tid] & 16383;
  __syncthreads();
  for (int e = tid; e < 32 * 128; e += 128) {
    const int k2 = e >> 7, d = e & 127;
    sm[k2 * 129 + d] = ego[tki[k2] * 128 + d];
  }
  __syncthreads();
  {
    const int kk = tid & 31, part = tid >> 5;
    float s = 0.f;
    const int d0 = part * 32;
    for (int d = d0; d < d0 + 32; ++d) s += qv[d] * sm[kk * 129 + d];
    psum[tid] = s;
  }
  __syncthreads();
  if (tid < 32) {
    float v = psum[tid] + psum[tid + 32] + psum[tid + 64] + psum[tid + 96];
    v *= (1.0f / 11.313708498984760f);    // 1/sqrt(128)
    float m = v;
#pragma unroll
    for (int off = 16; off; off >>= 1) m = fmaxf(m, __shfl_xor(m, off, 32));
    const float e = expf(v - m);
    float ssum = e;
#pragma unroll
    for (int off = 16; off; off >>= 1) ssum += __shfl_xor(ssum, off, 32);
    sc[tid] = e / ssum;
  }
  __syncthreads();
  float sad = 0.f;
  for (int k2 = 0; k2 < 32; ++k2) sad += sc[k2] * sm[k2 * 129 + tid];
  sa[tid] = sad;
  __syncthreads();
  float o = bv[tid];
  for (int d = 0; d < 128; ++d) o += sa[d] * wvT[d * 128 + tid];
  atten[n * 128 + tid] = o + 0.1f * ego[n * 128 + tid];
}

// ------------------------------------------------------- fusion -------------
__global__ __launch_bounds__(128) void k_fuse1(const float* __restrict__ allemb,
                                               const float* __restrict__ atten,
                                               const float* __restrict__ fw,
                                               const float* __restrict__ fb,
                                               float* __restrict__ z1,
                                               float* __restrict__ z2,
                                               float* __restrict__ cs1,
                                               float* __restrict__ cs2) {
  __shared__ float fwT[128 * 129];
  __shared__ float xr[128], ar[128];
  const int tid = threadIdx.x;
  for (int it = 0; it < 128; ++it) fwT[tid * 129 + it] = fw[it * 128 + tid];
  const float fbj = fb[tid];
  float ls1 = 0.f, ls2 = 0.f;
  const int r0 = blockIdx.x * 64;
  for (int rr = 0; rr < 64; ++rr) {
    const int r = r0 + rr;
    __syncthreads();
    xr[tid] = allemb[r * 128 + tid];
    ar[tid] = atten[r * 128 + tid];
    __syncthreads();
    float a1 = fbj, a2 = fbj;
    for (int d = 0; d < 128; ++d) {
      const float wgt = fwT[d * 129 + tid];
      a1 += xr[d] * wgt;
      a2 += ar[d] * wgt;
    }
    const float t1 = tanhf(a1), t2 = tanhf(a2);
    z1[r * 128 + tid] = t1;
    z2[r * 128 + tid] = t2;
    ls1 += expf(t1 - 1.0f);
    ls2 += expf(t2 - 1.0f);
  }
  atomicAdd(&cs1[tid], ls1);
  atomicAdd(&cs2[tid], ls2);
}

__global__ void k_fuse2(const float* __restrict__ allemb, const float* __restrict__ atten,
                        const float* __restrict__ z1, const float* __restrict__ z2,
                        const float* __restrict__ cs1, const float* __restrict__ cs2,
                        float* __restrict__ fusion) {
  const int i = blockIdx.x * 256 + threadIdx.x;
  const int j = i & 127;
  const float a1 = expf(z1[i] - 1.0f) / cs1[j];
  const float a2 = expf(z2[i] - 1.0f) / cs2[j];
  fusion[i] = a1 * allemb[i] + a2 * atten[i];
}

// ---------------------------------------------------------------- launch ----
extern "C" void kernel_launch(void* const* d_in, const int* in_sizes, int n_in,
                              void* d_out, int out_size, void* d_ws, size_t ws_size,
                              hipStream_t stream) {
  (void)in_sizes; (void)n_in; (void)out_size; (void)ws_size;
  const float* user = (const float*)d_in[0];
  const float* item = (const float*)d_in[1];
  const int* adj_rows = (const int*)d_in[2];
  const int* adj_cols = (const int*)d_in[3];
  const float* adj_vals = (const float*)d_in[4];
  const float* wq = (const float*)d_in[5];
  const float* bq = (const float*)d_in[6];
  const float* wk = (const float*)d_in[7];
  const float* wv = (const float*)d_in[9];
  const float* bv = (const float*)d_in[10];
  const float* fw = (const float*)d_in[11];
  const float* fb = (const float*)d_in[12];

  float* out = (float*)d_out;
  float* allemb = out;                    // [N,D]
  float* atten = out + (size_t)N_ * D_;   // [N,D]
  float* fusion = out + (size_t)2 * N_ * D_;

  char* ws = (char*)d_ws;
  size_t off = 0;
  auto alloc = [&](size_t bytes) { char* p = ws + off; off += (bytes + 255) & ~(size_t)255; return p; };
  float* ego_a = (float*)alloc((size_t)N_ * D_ * 4);
  float* ego_b = (float*)alloc((size_t)N_ * D_ * 4);
  float* qkbuf = (float*)alloc((size_t)N_ * D_ * 4);
  u16* Gh = (u16*)alloc((size_t)N_ * D_ * 2);
  u16* Gl = (u16*)alloc((size_t)N_ * D_ * 2);
  u16* XTh = (u16*)alloc((size_t)N_ * D_ * 2);
  u16* XTl = (u16*)alloc((size_t)N_ * D_ * 2);
  int2* gbuf = (int2*)alloc((size_t)N_ * CAP_ * 8);  // (col,val) pairs (aliased by z1)
  float* z1 = (float*)gbuf;                          // lifetimes disjoint
  float* z2 = (float*)alloc((size_t)N_ * D_ * 4);
  int* topk_idx = (int*)alloc((size_t)N_ * 32 * 4);
  int* ccol = (int*)alloc((size_t)E_ * 4);
  float* cval = (float*)alloc((size_t)E_ * 4);
  int* cnt = (int*)alloc((size_t)N_ * 4);
  int* row_ptr = (int*)alloc((size_t)(N_ + 1) * 4);
  int* cursor = (int*)alloc((size_t)N_ * 4);
  float* M = (float*)alloc(128 * 128 * 4);
  float* bqk = (float*)alloc(128 * 4);
  float* wvT = (float*)alloc(128 * 128 * 4);
  float* cs1 = (float*)alloc(128 * 4);
  float* cs2 = (float*)alloc(128 * 4);
  float* C2 = (float*)alloc(128 * 128 * 4);
  float* svec = (float*)alloc(128 * 4);
  float* tau = (float*)alloc((size_t)N_ * 4);
  int* gcount = (int*)alloc((size_t)N_ * 4);
  int* failq = (int*)alloc(64 * 4);
  int* failn = (int*)alloc(4);
  double* fsim = (double*)alloc((size_t)64 * N_ * 8);

  k_init<<<64, 256, 0, stream>>>(wq, wk, bq, wv, M, bqk, wvT, cnt, cs1, cs2, C2, svec, gcount, failn);
  k_concat<<<8192, 256, 0, stream>>>(user, item, ego_a);
  k_hist<<<2048, 256, 0, stream>>>(adj_rows, cnt);
  k_scan<<<1, 1024, 0, stream>>>(cnt, row_ptr, cursor);
  k_scatter<<<2048, 256, 0, stream>>>(adj_rows, adj_cols, adj_vals, cursor, ccol, cval);

  k_spmm<<<N_, 128, 0, stream>>>(ego_a, ego_b, allemb, row_ptr, ccol, cval, 1);
  k_spmm<<<N_, 128, 0, stream>>>(ego_b, ego_a, allemb, row_ptr, ccol, cval, 0);
  k_spmm<<<N_, 128, 0, stream>>>(ego_a, ego_b, allemb, row_ptr, ccol, cval, 0);
  // ego3 = ego_b
  k_div3<<<8192, 256, 0, stream>>>(allemb);

  k_split_t<<<256, 256, 0, stream>>>(ego_b, Gh, Gl, XTh, XTl, svec);
  k_c2mfma<<<32, 256, 0, stream>>>(XTh, XTl, C2);
  k_tau<<<N_, 128, 0, stream>>>(ego_b, C2, svec, tau);

  k_qk<<<512, 128, 0, stream>>>(ego_b, M, bqk, qkbuf);
  k_simmfma<<<1088, 256, 0, stream>>>(Gh, Gl, tau, gcount, gbuf);   // triangular tile set
  k_check<<<64, 256, 0, stream>>>(gcount, failq, failn);
  k_refine<<<4096, 256, 0, stream>>>(gcount, gbuf, topk_idx);
  k_fallback<<<64, 256, 0, stream>>>(ego_b, failq, failn, fsim, topk_idx);
  k_attn<<<N_, 128, 0, stream>>>(ego_b, qkbuf, topk_idx, wvT, bv, atten);

  k_fuse1<<<256, 128, 0, stream>>>(allemb, atten, fw, fb, z1, z2, cs1, cs2);
  k_fuse2<<<8192, 256, 0, stream>>>(allemb, atten, z1, z2, cs1, cs2, fusion);
}

// Round 2
// 1170.835 us; speedup vs baseline: 1.1340x; 1.1340x over previous
//
#include <hip/hip_runtime.h>
#include <math.h>

#define U_ 8192
#define I_ 8192
#define D_ 128
#define E_ 524288
#define N_ 16384
#define K_ 32
#define CAP_ 512

typedef unsigned short u16;
typedef unsigned int u32;
typedef unsigned long long u64;
typedef __attribute__((ext_vector_type(8))) short bf16x8;
typedef __attribute__((ext_vector_type(4))) float f32x4;

// ---------------------------------------------------------------- init ------
__global__ void k_init(const float* __restrict__ wq, const float* __restrict__ wk,
                       const float* __restrict__ bq, const float* __restrict__ wv,
                       float* __restrict__ M, float* __restrict__ bqk,
                       float* __restrict__ wvT,
                       int* __restrict__ cnt, float* __restrict__ cs1,
                       float* __restrict__ cs2, float* __restrict__ C2,
                       float* __restrict__ svec, int* __restrict__ gcount,
                       int* __restrict__ failn) {
  const int tid = blockIdx.x * 256 + threadIdx.x;   // 64 blocks -> 16384 threads
  cnt[tid] = 0;
  gcount[tid] = 0;
  C2[tid] = 0.f;
  if (tid < 128) { cs1[tid] = 0.f; cs2[tid] = 0.f; svec[tid] = 0.f; }
  if (tid == 0) *failn = 0;
  // M[i][j] = sum_l wq[l,i]*wk[l,j]  (wq^T wk)
  const int i = tid >> 7, j = tid & 127;
  float s = 0.f;
  for (int l = 0; l < 128; ++l) s += wq[l * 128 + i] * wk[l * 128 + j];
  M[tid] = s;
  wvT[i * 128 + j] = wv[j * 128 + i];
  if (tid < 128) {
    float s2 = 0.f;
    for (int l = 0; l < 128; ++l) s2 += bq[l] * wk[l * 128 + tid];
    bqk[tid] = s2;
  }
}

__global__ void k_concat(const float* __restrict__ user, const float* __restrict__ item,
                         float* __restrict__ ego) {
  const int i = blockIdx.x * 256 + threadIdx.x;     // 8192 blocks, exact
  ego[i] = (i < U_ * D_) ? user[i] : item[i - U_ * D_];
}

// ---------------------------------------------------------------- CSR -------
__global__ void k_hist(const int* __restrict__ rows, int* __restrict__ cnt) {
  const int e = blockIdx.x * 256 + threadIdx.x;     // 2048 blocks, exact
  atomicAdd(&cnt[rows[e]], 1);
}

__global__ void k_scan(const int* __restrict__ cnt, int* __restrict__ row_ptr,
                       int* __restrict__ cursor) {
  __shared__ int buf[1024];
  __shared__ int carry;
  const int t = threadIdx.x;
  if (t == 0) carry = 0;
  __syncthreads();
  for (int c = 0; c < N_ / 1024; ++c) {
    const int x = cnt[c * 1024 + t];
    buf[t] = x;
    __syncthreads();
    for (int off = 1; off < 1024; off <<= 1) {
      int v = (t >= off) ? buf[t - off] : 0;
      __syncthreads();
      buf[t] += v;
      __syncthreads();
    }
    const int incl = buf[t];
    const int excl = carry + incl - x;
    row_ptr[c * 1024 + t] = excl;
    cursor[c * 1024 + t] = excl;
    __syncthreads();
    if (t == 1023) carry += incl;
    __syncthreads();
  }
  if (t == 0) row_ptr[N_] = carry;
}

__global__ void k_scatter(const int* __restrict__ rows, const int* __restrict__ cols,
                          const float* __restrict__ vals, int* __restrict__ cursor,
                          int* __restrict__ ccol, float* __restrict__ cval) {
  const int e = blockIdx.x * 256 + threadIdx.x;
  const int r = rows[e];
  const int p = atomicAdd(&cursor[r], 1);
  ccol[p] = cols[e];
  cval[p] = vals[e];
}

// ---------------------------------------------------------------- SpMM ------
__global__ __launch_bounds__(128) void k_spmm(const float* __restrict__ x,
                                              float* __restrict__ y,
                                              float* __restrict__ sum,
                                              const int* __restrict__ row_ptr,
                                              const int* __restrict__ ccol,
                                              const float* __restrict__ cval,
                                              const int first) {
  const int r = blockIdx.x, d = threadIdx.x;
  const int b = row_ptr[r], e = row_ptr[r + 1];
  double acc = 0.0;
  for (int i = b; i < e; ++i)
    acc += (double)cval[i] * (double)x[ccol[i] * 128 + d];
  const float f = (float)acc;
  y[r * 128 + d] = f;
  if (first) sum[r * 128 + d] = f; else sum[r * 128 + d] += f;
}

__global__ void k_div3(float* __restrict__ a) {
  const int i = blockIdx.x * 256 + threadIdx.x;
  a[i] = a[i] / 3.0f;
}

// ------------------------------------------------- split + transpose --------
__global__ __launch_bounds__(256) void k_split_t(const float* __restrict__ x,
                                                 u16* __restrict__ Gh, u16* __restrict__ Gl,
                                                 u16* __restrict__ XTh, u16* __restrict__ XTl,
                                                 float* __restrict__ svec) {
  __shared__ u16 lh[128 * 66];
  __shared__ u16 ll[128 * 66];
  const int tid = threadIdx.x;
  const int r0 = blockIdx.x * 64;
  float colsum = 0.f;
  for (int s = 0; s < 32; ++s) {
    const int idx = tid + s * 256;
    const int r = idx >> 7, d = idx & 127;
    const float v = x[(r0 + r) * 128 + d];
    colsum += v;
    unsigned int u = __float_as_uint(v);
    u += 0x7fffu + ((u >> 16) & 1u);
    const u16 h = (u16)(u >> 16);
    const float hf = __uint_as_float(((unsigned int)h) << 16);
    const float l = v - hf;
    unsigned int u2 = __float_as_uint(l);
    u2 += 0x7fffu + ((u2 >> 16) & 1u);
    const u16 lo = (u16)(u2 >> 16);
    Gh[(r0 + r) * 128 + d] = h;
    Gl[(r0 + r) * 128 + d] = lo;
    lh[d * 66 + r] = h;
    ll[d * 66 + r] = lo;
  }
  atomicAdd(&svec[tid & 127], colsum);
  __syncthreads();
  for (int s = 0; s < 32; ++s) {
    const int idx = tid + s * 256;
    const int d = idx >> 6, rr = idx & 63;
    XTh[d * 16384 + r0 + rr] = lh[d * 66 + rr];
    XTl[d * 16384 + r0 + rr] = ll[d * 66 + rr];
  }
}

// ---------------------------------------------------------------- C2 --------
__global__ __launch_bounds__(256) void k_c2mfma(const u16* __restrict__ XTh,
                                                const u16* __restrict__ XTl,
                                                float* __restrict__ C2) {
  const int tid = threadIdx.x, w = tid >> 6, lane = tid & 63;
  const int n16 = lane & 15, kq = lane >> 4;
  const int c0 = blockIdx.x * 512;
  f32x4 acc[2][8];
#pragma unroll
  for (int a = 0; a < 2; ++a)
#pragma unroll
    for (int b = 0; b < 8; ++b) acc[a][b] = (f32x4){0.f, 0.f, 0.f, 0.f};
  for (int ks = 0; ks < 16; ++ks) {
    const int c = c0 + ks * 32 + kq * 8;
    bf16x8 Fh[8], Fl[8];
#pragma unroll
    for (int g = 0; g < 8; ++g) {
      const int base = (g * 16 + n16) * 16384 + c;
      Fh[g] = *(const bf16x8*)&XTh[base];
      Fl[g] = *(const bf16x8*)&XTl[base];
    }
#pragma unroll
    for (int a = 0; a < 2; ++a) {
      const int tr = w * 2 + a;
#pragma unroll
      for (int b = 0; b < 8; ++b) {
        acc[a][b] = __builtin_amdgcn_mfma_f32_16x16x32_bf16(Fl[tr], Fh[b], acc[a][b], 0, 0, 0);
        acc[a][b] = __builtin_amdgcn_mfma_f32_16x16x32_bf16(Fh[tr], Fl[b], acc[a][b], 0, 0, 0);
        acc[a][b] = __builtin_amdgcn_mfma_f32_16x16x32_bf16(Fh[tr], Fh[b], acc[a][b], 0, 0, 0);
      }
    }
  }
#pragma unroll
  for (int a = 0; a < 2; ++a) {
    const int tr = w * 2 + a;
#pragma unroll
    for (int b = 0; b < 8; ++b)
#pragma unroll
      for (int i = 0; i < 4; ++i)
        atomicAdd(&C2[(tr * 16 + kq * 4 + i) * 128 + b * 16 + n16], acc[a][b][i]);
  }
}

// tau_r = mean_r + 2.55 * sigma_r. Containment is STRUCTURAL: count>=36
// guarantees the top-32 (by our scores) all exceed tau; tau only trades
// candidate volume vs fallback frequency.
__global__ __launch_bounds__(128) void k_tau(const float* __restrict__ x,
                                             const float* __restrict__ C2,
                                             const float* __restrict__ svec,
                                             float* __restrict__ tau) {
  __shared__ float xs[128];
  __shared__ double red[128];
  const int n = blockIdx.x, tid = threadIdx.x;
  xs[tid] = x[n * 128 + tid];
  __syncthreads();
  double y = 0.0;
  for (int k2 = 0; k2 < 128; ++k2) y += (double)xs[k2] * (double)C2[k2 * 128 + tid];
  red[tid] = (double)xs[tid] * y;
  __syncthreads();
  for (int s = 64; s; s >>= 1) { if (tid < s) red[tid] += red[tid + s]; __syncthreads(); }
  const double exy = red[0] / 16384.0;
  __syncthreads();
  red[tid] = (double)xs[tid] * (double)svec[tid];
  __syncthreads();
  for (int s = 64; s; s >>= 1) { if (tid < s) red[tid] += red[tid + s]; __syncthreads(); }
  if (tid == 0) {
    const double m = red[0] / 16384.0;
    double var = exy - m * m;
    if (var < 0.0) var = 0.0;
    tau[n] = (float)(m + 2.55 * sqrt(var));
  }
}

// ---------------------------------------------------------------- qk --------
__global__ __launch_bounds__(128) void k_qk(const float* __restrict__ ego,
                                            const float* __restrict__ M,
                                            const float* __restrict__ bqk,
                                            float* __restrict__ qkout) {
  __shared__ float Ml[128 * 128];
  __shared__ float xr[128];
  const int tid = threadIdx.x;
  for (int e = tid; e < 16384; e += 128) Ml[e] = M[e];
  const float bj = bqk[tid];
  for (int r = blockIdx.x; r < N_; r += gridDim.x) {
    __syncthreads();
    xr[tid] = ego[r * 128 + tid];
    __syncthreads();
    float a = bj;
    for (int d = 0; d < 128; ++d) a += xr[d] * Ml[d * 128 + tid];
    qkout[r * 128 + tid] = a;
  }
}

// ------------------------------------------------------- sim via MFMA -------
// Round-2 structure: DENSE tile set (2048 blocks, single-sided scatter,
// identical candidate semantics to the verified round-0 kernel) but with
// NO LDS AND NO BARRIERS.  Round-1 post-mortem showed this kernel is
// latency/sync-bound (85% issue-idle at low occupancy), so the A-tile is
// now read straight from global per wave: the 4 waves of a block re-read
// the same 16x128 A-subtile through L1/L2 instead of sharing it via LDS.
// HBM traffic is unchanged; the default bid%8 XCD round-robin already
// pins each column-strip (bid%16==strip => bid%8==strip%8) to one XCD,
// so the 256KB strip is L2-resident and shared by its 128 row-blocks.
// With LDS=0 and no syncs, all 8 blocks/CU of the grid can be resident
// (32 waves/CU) and every stall is TLP-hidden.
__global__ __launch_bounds__(256) void k_simmfma(const u16* __restrict__ Gh,
                                                 const u16* __restrict__ Gl,
                                                 const float* __restrict__ tau,
                                                 int* __restrict__ gcount,
                                                 int2* __restrict__ gbuf) {
  const int tid = threadIdx.x;
  const int w = tid >> 6, lane = tid & 63;
  const int strip = blockIdx.x & 15, rgrp = blockIdx.x >> 4;
  const int n16 = lane & 15, kq = lane >> 4;

  const int rowbase = rgrp * 128 + w * 32;
  bf16x8 Bh[2][4], Bl[2][4];
#pragma unroll
  for (int rg = 0; rg < 2; ++rg) {
    const int row = rowbase + rg * 16 + n16;
#pragma unroll
    for (int q = 0; q < 4; ++q) {
      Bh[rg][q] = *(const bf16x8*)&Gh[row * 128 + q * 32 + kq * 8];
      Bl[rg][q] = *(const bf16x8*)&Gl[row * 128 + q * 32 + kq * 8];
    }
  }
  const float tau0 = tau[rowbase + n16];
  const float tau1 = tau[rowbase + 16 + n16];
  const int col0 = strip * 1024;

  for (int st = 0; st < 16; ++st) {
    const int cb = col0 + st * 64;
#pragma unroll
    for (int ct = 0; ct < 4; ++ct) {
      const int ar = cb + ct * 16 + n16;               // A row for this lane
      bf16x8 Ah[4];
#pragma unroll
      for (int q = 0; q < 4; ++q)
        Ah[q] = *(const bf16x8*)&Gh[(size_t)ar * 128 + q * 32 + kq * 8];
#pragma unroll
      for (int rg = 0; rg < 2; ++rg) {
        f32x4 p = {0.f, 0.f, 0.f, 0.f};
        f32x4 r = {0.f, 0.f, 0.f, 0.f};
#pragma unroll
        for (int q = 0; q < 4; ++q) {
          p = __builtin_amdgcn_mfma_f32_16x16x32_bf16(Ah[q], Bh[rg][q], p, 0, 0, 0);
          r = __builtin_amdgcn_mfma_f32_16x16x32_bf16(Ah[q], Bl[rg][q], r, 0, 0, 0);
        }
        const float tv = rg ? tau1 : tau0;
        const int row = rowbase + rg * 16 + n16;
#pragma unroll
        for (int i = 0; i < 4; ++i) {
          const float v = p[i] + r[i];
          if (v > tv) {
            const int c = cb + ct * 16 + kq * 4 + i;
            const int pos = atomicAdd(&gcount[row], 1);
            if (pos < CAP_) gbuf[row * CAP_ + pos] = make_int2(c, __float_as_int(v));
          }
        }
      }
    }
  }
}

// rows whose candidate count violates [36,CAP_] go to the exact fallback
__global__ void k_check(const int* __restrict__ gcount, int* __restrict__ failq,
                        int* __restrict__ failn) {
  const int n = blockIdx.x * 256 + threadIdx.x;   // 64 blocks
  const int c = gcount[n];
  if (c < 36 || c > CAP_) {
    const int s = atomicAdd(failn, 1);
    if (s < 64) failq[s] = n;
  }
}

// Top-32 by stored fp32 sim values via RANK-SCATTER on packed u64 keys:
// key = (sortable_f32 << 32) | (16383 - col)  -> (val desc, col asc) order.
// rank = #{keys greater}; rank<32 scatters directly. One wave per row.
__global__ __launch_bounds__(256) void k_refine(const int* __restrict__ gcount,
                                                const int2* __restrict__ gbuf,
                                                int* __restrict__ topk_idx) {
  __shared__ u64 lk[4][CAP_];
  const int tid = threadIdx.x, w = tid >> 6, lane = tid & 63;
  const int n = blockIdx.x * 4 + w;
  const int craw = gcount[n];
  const int bad = (craw < 36 || craw > CAP_);
  const int cnt = bad ? 0 : craw;

  u64 ku[CAP_ / 64];
  int kc[CAP_ / 64];
#pragma unroll
  for (int s = 0; s < CAP_ / 64; ++s) {
    ku[s] = 0; kc[s] = 0;
    const int ci = lane + s * 64;
    if (ci < cnt) {
      const int2 p = gbuf[n * CAP_ + ci];
      u32 uv = (u32)p.y;
      uv = (uv >> 31) ? ~uv : (uv | 0x80000000u);
      const u64 key = ((u64)uv << 32) | (u64)(16383 - p.x);
      lk[w][ci] = key;
      ku[s] = key;
      kc[s] = p.x;
    }
  }
  __syncthreads();

#pragma unroll
  for (int s = 0; s < CAP_ / 64; ++s) {
    const int ci = lane + s * 64;
    if (ci < cnt) {
      const u64 kk = ku[s];
      int r = 0;
#pragma unroll 4
      for (int j = 0; j < cnt; ++j)
        r += (lk[w][j] > kk) ? 1 : 0;
      if (r < 32) topk_idx[n * 32 + r] = kc[s];
    }
  }
  if (bad && lane < 32) topk_idx[n * 32 + lane] = 0;  // placeholder; fallback overwrites
}

// exact fp64 full-row top-32 for statistically-failed rows (expected: none)
__global__ __launch_bounds__(256) void k_fallback(const float* __restrict__ x,
                                                  const int* __restrict__ failq,
                                                  const int* __restrict__ failn,
                                                  double* __restrict__ fsim,
                                                  int* __restrict__ topk_idx) {
  const int nf = *failn;
  const int which = blockIdx.x;
  if (which >= nf || which >= 64) return;
  const int row = failq[which];
  __shared__ float xs[128];
  __shared__ double bm[256];
  __shared__ int bc[256];
  const int tid = threadIdx.x;
  if (tid < 128) xs[tid] = x[row * 128 + tid];
  __syncthreads();
  double* fs = fsim + (size_t)which * 16384;
  for (int c = tid; c < 16384; c += 256) {
    const float4* xp = (const float4*)&x[c * 128];
    double a = 0.0;
    for (int d = 0; d < 32; ++d) {
      const float4 v = xp[d];
      a += (double)xs[d * 4 + 0] * (double)v.x + (double)xs[d * 4 + 1] * (double)v.y +
           (double)xs[d * 4 + 2] * (double)v.z + (double)xs[d * 4 + 3] * (double)v.w;
    }
    fs[c] = a;
  }
  __syncthreads();
  for (int r = 0; r < 32; ++r) {
    double m = -1.0e300; int mc = 0;
    for (int c = tid; c < 16384; c += 256) {
      const double v = fs[c];
      if (v > m || (v == m && c < mc)) { m = v; mc = c; }
    }
    bm[tid] = m; bc[tid] = mc;
    __syncthreads();
    for (int s = 128; s; s >>= 1) {
      if (tid < s) {
        if (bm[tid + s] > bm[tid] || (bm[tid + s] == bm[tid] && bc[tid + s] < bc[tid])) {
          bm[tid] = bm[tid + s]; bc[tid] = bc[tid + s];
        }
      }
      __syncthreads();
    }
    if (tid == 0) { topk_idx[row * 32 + r] = bc[0]; fs[bc[0]] = -1.0e300; }
    __syncthreads();
  }
}

// ------------------------------------------------------- attention ----------
__global__ __launch_bounds__(128) void k_attn(const float* __restrict__ ego,
                                              const float* __restrict__ qk,
                                              const int* __restrict__ topk_idx,
                                              const float* __restrict__ wvT,
                                              const float* __restrict__ bv,
                                              float* __restrict__ atten) {
  __shared__ float qv[128];
  __shared__ float sm[32 * 129];
  __shared__ int tki[32];
  __shared__ float sc[32];
  __shared__ float sa[128];
  __shared__ float psum[128];
  const int n = blockIdx.x, tid = threadIdx.x;
  qv[tid] = qk[n * 128 + tid];
  if (tid < 32) tki[tid] = topk_idx[n * 32 + tid] & 16383;
  __syncthreads();
  for (int e = tid; e < 32 * 128; e += 128) {
    const int k2 = e >> 7, d = e & 127;
    sm[k2 * 129 + d] = ego[tki[k2] * 128 + d];
  }
  __syncthreads();
  {
    const int kk = tid & 31, part = tid >> 5;
    float s = 0.f;
    const int d0 = part * 32;
    for (int d = d0; d < d0 + 32; ++d) s += qv[d] * sm[kk * 129 + d];
    psum[tid] = s;
  }
  __syncthreads();
  if (tid < 32) {
    float v = psum[tid] + psum[tid + 32] + psum[tid + 64] + psum[tid + 96];
    v *= (1.0f / 11.313708498984760f);    // 1/sqrt(128)
    float m = v;
#pragma unroll
    for (int off = 16; off; off >>= 1) m = fmaxf(m, __shfl_xor(m, off, 32));
    const float e = expf(v - m);
    float ssum = e;
#pragma unroll
    for (int off = 16; off; off >>= 1) ssum += __shfl_xor(ssum, off, 32);
    sc[tid] = e / ssum;
  }
  __syncthreads();
  float sad = 0.f;
  for (int k2 = 0; k2 < 32; ++k2) sad += sc[k2] * sm[k2 * 129 + tid];
  sa[tid] = sad;
  __syncthreads();
  float o = bv[tid];
  for (int d = 0; d < 128; ++d) o += sa[d] * wvT[d * 128 + tid];
  atten[n * 128 + tid] = o + 0.1f * ego[n * 128 + tid];
}

// ------------------------------------------------------- fusion -------------
__global__ __launch_bounds__(128) void k_fuse1(const float* __restrict__ allemb,
                                               const float* __restrict__ atten,
                                               const float* __restrict__ fw,
                                               const float* __restrict__ fb,
                                               float* __restrict__ z1,
                                               float* __restrict__ z2,
                                               float* __restrict__ cs1,
                                               float* __restrict__ cs2) {
  __shared__ float fwT[128 * 129];
  __shared__ float xr[128], ar[128];
  const int tid = threadIdx.x;
  for (int it = 0; it < 128; ++it) fwT[tid * 129 + it] = fw[it * 128 + tid];
  const float fbj = fb[tid];
  float ls1 = 0.f, ls2 = 0.f;
  const int r0 = blockIdx.x * 64;
  for (int rr = 0; rr < 64; ++rr) {
    const int r = r0 + rr;
    __syncthreads();
    xr[tid] = allemb[r * 128 + tid];
    ar[tid] = atten[r * 128 + tid];
    __syncthreads();
    float a1 = fbj, a2 = fbj;
    for (int d = 0; d < 128; ++d) {
      const float wgt = fwT[d * 129 + tid];
      a1 += xr[d] * wgt;
      a2 += ar[d] * wgt;
    }
    const float t1 = tanhf(a1), t2 = tanhf(a2);
    z1[r * 128 + tid] = t1;
    z2[r * 128 + tid] = t2;
    ls1 += expf(t1 - 1.0f);
    ls2 += expf(t2 - 1.0f);
  }
  atomicAdd(&cs1[tid], ls1);
  atomicAdd(&cs2[tid], ls2);
}

__global__ void k_fuse2(const float* __restrict__ allemb, const float* __restrict__ atten,
                        const float* __restrict__ z1, const float* __restrict__ z2,
                        const float* __restrict__ cs1, const float* __restrict__ cs2,
                        float* __restrict__ fusion) {
  const int i = blockIdx.x * 256 + threadIdx.x;
  const int j = i & 127;
  const float a1 = expf(z1[i] - 1.0f) / cs1[j];
  const float a2 = expf(z2[i] - 1.0f) / cs2[j];
  fusion[i] = a1 * allemb[i] + a2 * atten[i];
}

// ---------------------------------------------------------------- launch ----
extern "C" void kernel_launch(void* const* d_in, const int* in_sizes, int n_in,
                              void* d_out, int out_size, void* d_ws, size_t ws_size,
                              hipStream_t stream) {
  (void)in_sizes; (void)n_in; (void)out_size; (void)ws_size;
  const float* user = (const float*)d_in[0];
  const float* item = (const float*)d_in[1];
  const int* adj_rows = (const int*)d_in[2];
  const int* adj_cols = (const int*)d_in[3];
  const float* adj_vals = (const float*)d_in[4];
  const float* wq = (const float*)d_in[5];
  const float* bq = (const float*)d_in[6];
  const float* wk = (const float*)d_in[7];
  const float* wv = (const float*)d_in[9];
  const float* bv = (const float*)d_in[10];
  const float* fw = (const float*)d_in[11];
  const float* fb = (const float*)d_in[12];

  float* out = (float*)d_out;
  float* allemb = out;                    // [N,D]
  float* atten = out + (size_t)N_ * D_;   // [N,D]
  float* fusion = out + (size_t)2 * N_ * D_;

  char* ws = (char*)d_ws;
  size_t off = 0;
  auto alloc = [&](size_t bytes) { char* p = ws + off; off += (bytes + 255) & ~(size_t)255; return p; };
  float* ego_a = (float*)alloc((size_t)N_ * D_ * 4);
  float* ego_b = (float*)alloc((size_t)N_ * D_ * 4);
  float* qkbuf = (float*)alloc((size_t)N_ * D_ * 4);
  u16* Gh = (u16*)alloc((size_t)N_ * D_ * 2);
  u16* Gl = (u16*)alloc((size_t)N_ * D_ * 2);
  u16* XTh = (u16*)alloc((size_t)N_ * D_ * 2);
  u16* XTl = (u16*)alloc((size_t)N_ * D_ * 2);
  int2* gbuf = (int2*)alloc((size_t)N_ * CAP_ * 8);  // (col,val) pairs (aliased by z1)
  float* z1 = (float*)gbuf;                          // lifetimes disjoint
  float* z2 = (float*)alloc((size_t)N_ * D_ * 4);
  int* topk_idx = (int*)alloc((size_t)N_ * 32 * 4);
  int* ccol = (int*)alloc((size_t)E_ * 4);
  float* cval = (float*)alloc((size_t)E_ * 4);
  int* cnt = (int*)alloc((size_t)N_ * 4);
  int* row_ptr = (int*)alloc((size_t)(N_ + 1) * 4);
  int* cursor = (int*)alloc((size_t)N_ * 4);
  float* M = (float*)alloc(128 * 128 * 4);
  float* bqk = (float*)alloc(128 * 4);
  float* wvT = (float*)alloc(128 * 128 * 4);
  float* cs1 = (float*)alloc(128 * 4);
  float* cs2 = (float*)alloc(128 * 4);
  float* C2 = (float*)alloc(128 * 128 * 4);
  float* svec = (float*)alloc(128 * 4);
  float* tau = (float*)alloc((size_t)N_ * 4);
  int* gcount = (int*)alloc((size_t)N_ * 4);
  int* failq = (int*)alloc(64 * 4);
  int* failn = (int*)alloc(4);
  double* fsim = (double*)alloc((size_t)64 * N_ * 8);

  k_init<<<64, 256, 0, stream>>>(wq, wk, bq, wv, M, bqk, wvT, cnt, cs1, cs2, C2, svec, gcount, failn);
  k_concat<<<8192, 256, 0, stream>>>(user, item, ego_a);
  k_hist<<<2048, 256, 0, stream>>>(adj_rows, cnt);
  k_scan<<<1, 1024, 0, stream>>>(cnt, row_ptr, cursor);
  k_scatter<<<2048, 256, 0, stream>>>(adj_rows, adj_cols, adj_vals, cursor, ccol, cval);

  k_spmm<<<N_, 128, 0, stream>>>(ego_a, ego_b, allemb, row_ptr, ccol, cval, 1);
  k_spmm<<<N_, 128, 0, stream>>>(ego_b, ego_a, allemb, row_ptr, ccol, cval, 0);
  k_spmm<<<N_, 128, 0, stream>>>(ego_a, ego_b, allemb, row_ptr, ccol, cval, 0);
  // ego3 = ego_b
  k_div3<<<8192, 256, 0, stream>>>(allemb);

  k_split_t<<<256, 256, 0, stream>>>(ego_b, Gh, Gl, XTh, XTl, svec);
  k_c2mfma<<<32, 256, 0, stream>>>(XTh, XTl, C2);
  k_tau<<<N_, 128, 0, stream>>>(ego_b, C2, svec, tau);

  k_qk<<<512, 128, 0, stream>>>(ego_b, M, bqk, qkbuf);
  k_simmfma<<<2048, 256, 0, stream>>>(Gh, Gl, tau, gcount, gbuf);   // dense, barrier-free
  k_check<<<64, 256, 0, stream>>>(gcount, failq, failn);
  k_refine<<<4096, 256, 0, stream>>>(gcount, gbuf, topk_idx);
  k_fallback<<<64, 256, 0, stream>>>(ego_b, failq, failn, fsim, topk_idx);
  k_attn<<<N_, 128, 0, stream>>>(ego_b, qkbuf, topk_idx, wvT, bv, atten);

  k_fuse1<<<256, 128, 0, stream>>>(allemb, atten, fw, fb, z1, z2, cs1, cs2);
  k_fuse2<<<8192, 256, 0, stream>>>(allemb, atten, z1, z2, cs1, cs2, fusion);
}

// Round 3
// 1125.804 us; speedup vs baseline: 1.1794x; 1.0400x over previous
//
#include <hip/hip_runtime.h>
#include <math.h>

#define U_ 8192
#define I_ 8192
#define D_ 128
#define E_ 524288
#define N_ 16384
#define K_ 32
#define CAP_ 512

typedef unsigned short u16;
typedef unsigned int u32;
typedef unsigned long long u64;
typedef __attribute__((ext_vector_type(8))) short bf16x8;
typedef __attribute__((ext_vector_type(4))) float f32x4;

// ---------------------------------------------------------------- init ------
__global__ void k_init(const float* __restrict__ wq, const float* __restrict__ wk,
                       const float* __restrict__ bq, const float* __restrict__ wv,
                       float* __restrict__ M, float* __restrict__ bqk,
                       float* __restrict__ wvT,
                       int* __restrict__ cnt, float* __restrict__ cs1,
                       float* __restrict__ cs2, float* __restrict__ C2,
                       float* __restrict__ svec, int* __restrict__ gcount,
                       int* __restrict__ failn) {
  const int tid = blockIdx.x * 256 + threadIdx.x;   // 64 blocks -> 16384 threads
  cnt[tid] = 0;
  gcount[tid] = 0;
  C2[tid] = 0.f;
  if (tid < 128) { cs1[tid] = 0.f; cs2[tid] = 0.f; svec[tid] = 0.f; }
  if (tid == 0) *failn = 0;
  // M[i][j] = sum_l wq[l,i]*wk[l,j]  (wq^T wk)
  const int i = tid >> 7, j = tid & 127;
  float s = 0.f;
  for (int l = 0; l < 128; ++l) s += wq[l * 128 + i] * wk[l * 128 + j];
  M[tid] = s;
  wvT[i * 128 + j] = wv[j * 128 + i];
  if (tid < 128) {
    float s2 = 0.f;
    for (int l = 0; l < 128; ++l) s2 += bq[l] * wk[l * 128 + tid];
    bqk[tid] = s2;
  }
}

__global__ void k_concat(const float* __restrict__ user, const float* __restrict__ item,
                         float* __restrict__ ego) {
  const int i = blockIdx.x * 256 + threadIdx.x;     // 8192 blocks, exact
  ego[i] = (i < U_ * D_) ? user[i] : item[i - U_ * D_];
}

// ---------------------------------------------------------------- CSR -------
__global__ void k_hist(const int* __restrict__ rows, int* __restrict__ cnt) {
  const int e = blockIdx.x * 256 + threadIdx.x;     // 2048 blocks, exact
  atomicAdd(&cnt[rows[e]], 1);
}

__global__ void k_scan(const int* __restrict__ cnt, int* __restrict__ row_ptr,
                       int* __restrict__ cursor) {
  __shared__ int buf[1024];
  __shared__ int carry;
  const int t = threadIdx.x;
  if (t == 0) carry = 0;
  __syncthreads();
  for (int c = 0; c < N_ / 1024; ++c) {
    const int x = cnt[c * 1024 + t];
    buf[t] = x;
    __syncthreads();
    for (int off = 1; off < 1024; off <<= 1) {
      int v = (t >= off) ? buf[t - off] : 0;
      __syncthreads();
      buf[t] += v;
      __syncthreads();
    }
    const int incl = buf[t];
    const int excl = carry + incl - x;
    row_ptr[c * 1024 + t] = excl;
    cursor[c * 1024 + t] = excl;
    __syncthreads();
    if (t == 1023) carry += incl;
    __syncthreads();
  }
  if (t == 0) row_ptr[N_] = carry;
}

__global__ void k_scatter(const int* __restrict__ rows, const int* __restrict__ cols,
                          const float* __restrict__ vals, int* __restrict__ cursor,
                          int* __restrict__ ccol, float* __restrict__ cval) {
  const int e = blockIdx.x * 256 + threadIdx.x;
  const int r = rows[e];
  const int p = atomicAdd(&cursor[r], 1);
  ccol[p] = cols[e];
  cval[p] = vals[e];
}

// ---------------------------------------------------------------- SpMM ------
__global__ __launch_bounds__(128) void k_spmm(const float* __restrict__ x,
                                              float* __restrict__ y,
                                              float* __restrict__ sum,
                                              const int* __restrict__ row_ptr,
                                              const int* __restrict__ ccol,
                                              const float* __restrict__ cval,
                                              const int first) {
  const int r = blockIdx.x, d = threadIdx.x;
  const int b = row_ptr[r], e = row_ptr[r + 1];
  double acc = 0.0;
  for (int i = b; i < e; ++i)
    acc += (double)cval[i] * (double)x[ccol[i] * 128 + d];
  const float f = (float)acc;
  y[r * 128 + d] = f;
  if (first) sum[r * 128 + d] = f; else sum[r * 128 + d] += f;
}

__global__ void k_div3(float* __restrict__ a) {
  const int i = blockIdx.x * 256 + threadIdx.x;
  a[i] = a[i] / 3.0f;
}

// ------------------------------------------------- split + transpose --------
__global__ __launch_bounds__(256) void k_split_t(const float* __restrict__ x,
                                                 u16* __restrict__ Gh, u16* __restrict__ Gl,
                                                 u16* __restrict__ XTh, u16* __restrict__ XTl,
                                                 float* __restrict__ svec) {
  __shared__ u16 lh[128 * 66];
  __shared__ u16 ll[128 * 66];
  const int tid = threadIdx.x;
  const int r0 = blockIdx.x * 64;
  float colsum = 0.f;
  for (int s = 0; s < 32; ++s) {
    const int idx = tid + s * 256;
    const int r = idx >> 7, d = idx & 127;
    const float v = x[(r0 + r) * 128 + d];
    colsum += v;
    unsigned int u = __float_as_uint(v);
    u += 0x7fffu + ((u >> 16) & 1u);
    const u16 h = (u16)(u >> 16);
    const float hf = __uint_as_float(((unsigned int)h) << 16);
    const float l = v - hf;
    unsigned int u2 = __float_as_uint(l);
    u2 += 0x7fffu + ((u2 >> 16) & 1u);
    const u16 lo = (u16)(u2 >> 16);
    Gh[(r0 + r) * 128 + d] = h;
    Gl[(r0 + r) * 128 + d] = lo;
    lh[d * 66 + r] = h;
    ll[d * 66 + r] = lo;
  }
  atomicAdd(&svec[tid & 127], colsum);
  __syncthreads();
  for (int s = 0; s < 32; ++s) {
    const int idx = tid + s * 256;
    const int d = idx >> 6, rr = idx & 63;
    XTh[d * 16384 + r0 + rr] = lh[d * 66 + rr];
    XTl[d * 16384 + r0 + rr] = ll[d * 66 + rr];
  }
}

// ---------------------------------------------------------------- C2 --------
__global__ __launch_bounds__(256) void k_c2mfma(const u16* __restrict__ XTh,
                                                const u16* __restrict__ XTl,
                                                float* __restrict__ C2) {
  const int tid = threadIdx.x, w = tid >> 6, lane = tid & 63;
  const int n16 = lane & 15, kq = lane >> 4;
  const int c0 = blockIdx.x * 512;
  f32x4 acc[2][8];
#pragma unroll
  for (int a = 0; a < 2; ++a)
#pragma unroll
    for (int b = 0; b < 8; ++b) acc[a][b] = (f32x4){0.f, 0.f, 0.f, 0.f};
  for (int ks = 0; ks < 16; ++ks) {
    const int c = c0 + ks * 32 + kq * 8;
    bf16x8 Fh[8], Fl[8];
#pragma unroll
    for (int g = 0; g < 8; ++g) {
      const int base = (g * 16 + n16) * 16384 + c;
      Fh[g] = *(const bf16x8*)&XTh[base];
      Fl[g] = *(const bf16x8*)&XTl[base];
    }
#pragma unroll
    for (int a = 0; a < 2; ++a) {
      const int tr = w * 2 + a;
#pragma unroll
      for (int b = 0; b < 8; ++b) {
        acc[a][b] = __builtin_amdgcn_mfma_f32_16x16x32_bf16(Fl[tr], Fh[b], acc[a][b], 0, 0, 0);
        acc[a][b] = __builtin_amdgcn_mfma_f32_16x16x32_bf16(Fh[tr], Fl[b], acc[a][b], 0, 0, 0);
        acc[a][b] = __builtin_amdgcn_mfma_f32_16x16x32_bf16(Fh[tr], Fh[b], acc[a][b], 0, 0, 0);
      }
    }
  }
#pragma unroll
  for (int a = 0; a < 2; ++a) {
    const int tr = w * 2 + a;
#pragma unroll
    for (int b = 0; b < 8; ++b)
#pragma unroll
      for (int i = 0; i < 4; ++i)
        atomicAdd(&C2[(tr * 16 + kq * 4 + i) * 128 + b * 16 + n16], acc[a][b][i]);
  }
}

// tau_r = mean_r + 2.55 * sigma_r. Containment is STRUCTURAL: count>=36
// guarantees the top-32 (by our scores) all exceed tau; tau only trades
// candidate volume vs fallback frequency.
__global__ __launch_bounds__(128) void k_tau(const float* __restrict__ x,
                                             const float* __restrict__ C2,
                                             const float* __restrict__ svec,
                                             float* __restrict__ tau) {
  __shared__ float xs[128];
  __shared__ double red[128];
  const int n = blockIdx.x, tid = threadIdx.x;
  xs[tid] = x[n * 128 + tid];
  __syncthreads();
  double y = 0.0;
  for (int k2 = 0; k2 < 128; ++k2) y += (double)xs[k2] * (double)C2[k2 * 128 + tid];
  red[tid] = (double)xs[tid] * y;
  __syncthreads();
  for (int s = 64; s; s >>= 1) { if (tid < s) red[tid] += red[tid + s]; __syncthreads(); }
  const double exy = red[0] / 16384.0;
  __syncthreads();
  red[tid] = (double)xs[tid] * (double)svec[tid];
  __syncthreads();
  for (int s = 64; s; s >>= 1) { if (tid < s) red[tid] += red[tid + s]; __syncthreads(); }
  if (tid == 0) {
    const double m = red[0] / 16384.0;
    double var = exy - m * m;
    if (var < 0.0) var = 0.0;
    tau[n] = (float)(m + 2.55 * sqrt(var));
  }
}

// ---------------------------------------------------------------- qk --------
__global__ __launch_bounds__(128) void k_qk(const float* __restrict__ ego,
                                            const float* __restrict__ M,
                                            const float* __restrict__ bqk,
                                            float* __restrict__ qkout) {
  __shared__ float Ml[128 * 128];
  __shared__ float xr[128];
  const int tid = threadIdx.x;
  for (int e = tid; e < 16384; e += 128) Ml[e] = M[e];
  const float bj = bqk[tid];
  for (int r = blockIdx.x; r < N_; r += gridDim.x) {
    __syncthreads();
    xr[tid] = ego[r * 128 + tid];
    __syncthreads();
    float a = bj;
    for (int d = 0; d < 128; ++d) a += xr[d] * Ml[d * 128 + tid];
    qkout[r * 128 + tid] = a;
  }
}

// ------------------------------------------------------- sim via MFMA -------
// Round-3: dense tile set (2048 blocks, single-sided scatter, round-0
// candidate semantics bit-for-bit) with a 2-PHASE DOUBLE-BUFFERED LDS
// pipeline.  Round-2 proved the LDS-shared dataflow is right (global
// re-reads were worse); round-0's cost was the serialized
// stage->barrier->compute->barrier schedule.  Now: tile st+1 is DMA'd via
// global_load_lds (width 16, source pre-swizzled so swizzled ds_reads are
// bank-spread -- mechanics harness-verified in round 1) into buf[cur^1]
// BEFORE computing tile st from buf[cur]; one __syncthreads per iteration
// (its implicit vmcnt/lgkmcnt drain makes the buffer flip race-free).
// Stage latency hides under the 256 MFMAs of the compute phase.
__device__ __forceinline__ void gload_lds16(const u16* g, u16* l) {
  __builtin_amdgcn_global_load_lds(
      (const __attribute__((address_space(1))) void*)g,
      (__attribute__((address_space(3))) void*)l, 16, 0, 0);
}

__global__ __launch_bounds__(256) void k_simmfma(const u16* __restrict__ Gh,
                                                 const u16* __restrict__ Gl,
                                                 const float* __restrict__ tau,
                                                 int* __restrict__ gcount,
                                                 int2* __restrict__ gbuf) {
  __shared__ __align__(16) u16 lh[2][64 * 128];   // 2 x 16 KB, linear 256-B rows
  const int tid = threadIdx.x;
  const int w = tid >> 6, lane = tid & 63;
  const int strip = blockIdx.x & 15, rgrp = blockIdx.x >> 4;
  const int n16 = lane & 15, kq = lane >> 4;

  const int rowbase = rgrp * 128 + w * 32;
  bf16x8 Bh[2][4], Bl[2][4];
#pragma unroll
  for (int rg = 0; rg < 2; ++rg) {
    const int row = rowbase + rg * 16 + n16;
#pragma unroll
    for (int q = 0; q < 4; ++q) {
      Bh[rg][q] = *(const bf16x8*)&Gh[row * 128 + q * 32 + kq * 8];
      Bl[rg][q] = *(const bf16x8*)&Gl[row * 128 + q * 32 + kq * 8];
    }
  }
  const float tau0 = tau[rowbase + n16];
  const float tau1 = tau[rowbase + 16 + n16];
  const int col0 = strip * 1024;

  // stage 64 rows x 256 B: each wave DMAs 4 rows per issue (1024 B);
  // global source chunk pre-swizzled (n16 ^ row&7) so LDS stays linear
  // and the swizzled read below finds its data bank-conflict-spread.
#define STAGE(buf, cb)                                                         \
  do {                                                                         \
    _Pragma("unroll")                                                          \
    for (int ii = 0; ii < 4; ++ii) {                                           \
      const int srow = w * 16 + ii * 4 + kq;                                   \
      const int chunk = n16 ^ (srow & 7);                                      \
      gload_lds16(Gh + (((size_t)((cb) + srow)) << 7) + chunk * 8,             \
                  lh[buf] + ((w * 16 + ii * 4) << 7));                         \
    }                                                                          \
  } while (0)

  STAGE(0, col0);
  __syncthreads();                                  // prologue drain
  int cur = 0;

  for (int st = 0; st < 16; ++st) {
    const int cb = col0 + st * 64;
    if (st < 15) STAGE(cur ^ 1, cb + 64);           // prefetch next tile

#pragma unroll
    for (int ct = 0; ct < 4; ++ct) {
      const int ar = ct * 16 + n16;
      const char* lbase = (const char*)lh[cur] + ar * 256;
      bf16x8 Ah[4];
#pragma unroll
      for (int q = 0; q < 4; ++q)
        Ah[q] = *(const bf16x8*)(lbase + ((q * 64 + kq * 16) ^ ((ar & 7) << 4)));
#pragma unroll
      for (int rg = 0; rg < 2; ++rg) {
        f32x4 p = {0.f, 0.f, 0.f, 0.f};
        f32x4 r = {0.f, 0.f, 0.f, 0.f};
#pragma unroll
        for (int q = 0; q < 4; ++q) {
          p = __builtin_amdgcn_mfma_f32_16x16x32_bf16(Ah[q], Bh[rg][q], p, 0, 0, 0);
          r = __builtin_amdgcn_mfma_f32_16x16x32_bf16(Ah[q], Bl[rg][q], r, 0, 0, 0);
        }
        const float tv = rg ? tau1 : tau0;
        const int row = rowbase + rg * 16 + n16;
#pragma unroll
        for (int i = 0; i < 4; ++i) {
          const float v = p[i] + r[i];
          if (v > tv) {
            const int c = cb + ct * 16 + kq * 4 + i;
            const int pos = atomicAdd(&gcount[row], 1);
            if (pos < CAP_) gbuf[row * CAP_ + pos] = make_int2(c, __float_as_int(v));
          }
        }
      }
    }
    __syncthreads();   // implicit vmcnt(0)+lgkmcnt(0): staging landed, reads done
    cur ^= 1;
  }
#undef STAGE
}

// rows whose candidate count violates [36,CAP_] go to the exact fallback
__global__ void k_check(const int* __restrict__ gcount, int* __restrict__ failq,
                        int* __restrict__ failn) {
  const int n = blockIdx.x * 256 + threadIdx.x;   // 64 blocks
  const int c = gcount[n];
  if (c < 36 || c > CAP_) {
    const int s = atomicAdd(failn, 1);
    if (s < 64) failq[s] = n;
  }
}

// Top-32 by stored fp32 sim values via RANK-SCATTER on packed u64 keys:
// key = (sortable_f32 << 32) | (16383 - col)  -> (val desc, col asc) order.
// rank = #{keys greater}; rank<32 scatters directly. One wave per row.
__global__ __launch_bounds__(256) void k_refine(const int* __restrict__ gcount,
                                                const int2* __restrict__ gbuf,
                                                int* __restrict__ topk_idx) {
  __shared__ u64 lk[4][CAP_];
  const int tid = threadIdx.x, w = tid >> 6, lane = tid & 63;
  const int n = blockIdx.x * 4 + w;
  const int craw = gcount[n];
  const int bad = (craw < 36 || craw > CAP_);
  const int cnt = bad ? 0 : craw;

  u64 ku[CAP_ / 64];
  int kc[CAP_ / 64];
#pragma unroll
  for (int s = 0; s < CAP_ / 64; ++s) {
    ku[s] = 0; kc[s] = 0;
    const int ci = lane + s * 64;
    if (ci < cnt) {
      const int2 p = gbuf[n * CAP_ + ci];
      u32 uv = (u32)p.y;
      uv = (uv >> 31) ? ~uv : (uv | 0x80000000u);
      const u64 key = ((u64)uv << 32) | (u64)(16383 - p.x);
      lk[w][ci] = key;
      ku[s] = key;
      kc[s] = p.x;
    }
  }
  __syncthreads();

#pragma unroll
  for (int s = 0; s < CAP_ / 64; ++s) {
    const int ci = lane + s * 64;
    if (ci < cnt) {
      const u64 kk = ku[s];
      int r = 0;
#pragma unroll 4
      for (int j = 0; j < cnt; ++j)
        r += (lk[w][j] > kk) ? 1 : 0;
      if (r < 32) topk_idx[n * 32 + r] = kc[s];
    }
  }
  if (bad && lane < 32) topk_idx[n * 32 + lane] = 0;  // placeholder; fallback overwrites
}

// exact fp64 full-row top-32 for statistically-failed rows (expected: none)
__global__ __launch_bounds__(256) void k_fallback(const float* __restrict__ x,
                                                  const int* __restrict__ failq,
                                                  const int* __restrict__ failn,
                                                  double* __restrict__ fsim,
                                                  int* __restrict__ topk_idx) {
  const int nf = *failn;
  const int which = blockIdx.x;
  if (which >= nf || which >= 64) return;
  const int row = failq[which];
  __shared__ float xs[128];
  __shared__ double bm[256];
  __shared__ int bc[256];
  const int tid = threadIdx.x;
  if (tid < 128) xs[tid] = x[row * 128 + tid];
  __syncthreads();
  double* fs = fsim + (size_t)which * 16384;
  for (int c = tid; c < 16384; c += 256) {
    const float4* xp = (const float4*)&x[c * 128];
    double a = 0.0;
    for (int d = 0; d < 32; ++d) {
      const float4 v = xp[d];
      a += (double)xs[d * 4 + 0] * (double)v.x + (double)xs[d * 4 + 1] * (double)v.y +
           (double)xs[d * 4 + 2] * (double)v.z + (double)xs[d * 4 + 3] * (double)v.w;
    }
    fs[c] = a;
  }
  __syncthreads();
  for (int r = 0; r < 32; ++r) {
    double m = -1.0e300; int mc = 0;
    for (int c = tid; c < 16384; c += 256) {
      const double v = fs[c];
      if (v > m || (v == m && c < mc)) { m = v; mc = c; }
    }
    bm[tid] = m; bc[tid] = mc;
    __syncthreads();
    for (int s = 128; s; s >>= 1) {
      if (tid < s) {
        if (bm[tid + s] > bm[tid] || (bm[tid + s] == bm[tid] && bc[tid + s] < bc[tid])) {
          bm[tid] = bm[tid + s]; bc[tid] = bc[tid + s];
        }
      }
      __syncthreads();
    }
    if (tid == 0) { topk_idx[row * 32 + r] = bc[0]; fs[bc[0]] = -1.0e300; }
    __syncthreads();
  }
}

// ------------------------------------------------------- attention ----------
__global__ __launch_bounds__(128) void k_attn(const float* __restrict__ ego,
                                              const float* __restrict__ qk,
                                              const int* __restrict__ topk_idx,
                                              const float* __restrict__ wvT,
                                              const float* __restrict__ bv,
                                              float* __restrict__ atten) {
  __shared__ float qv[128];
  __shared__ float sm[32 * 129];
  __shared__ int tki[32];
  __shared__ float sc[32];
  __shared__ float sa[128];
  __shared__ float psum[128];
  const int n = blockIdx.x, tid = threadIdx.x;
  qv[tid] = qk[n * 128 + tid];
  if (tid < 32) tki[tid] = topk_idx[n * 32 + tid] & 16383;
  __syncthreads();
  for (int e = tid; e < 32 * 128; e += 128) {
    const int k2 = e >> 7, d = e & 127;
    sm[k2 * 129 + d] = ego[tki[k2] * 128 + d];
  }
  __syncthreads();
  {
    const int kk = tid & 31, part = tid >> 5;
    float s = 0.f;
    const int d0 = part * 32;
    for (int d = d0; d < d0 + 32; ++d) s += qv[d] * sm[kk * 129 + d];
    psum[tid] = s;
  }
  __syncthreads();
  if (tid < 32) {
    float v = psum[tid] + psum[tid + 32] + psum[tid + 64] + psum[tid + 96];
    v *= (1.0f / 11.313708498984760f);    // 1/sqrt(128)
    float m = v;
#pragma unroll
    for (int off = 16; off; off >>= 1) m = fmaxf(m, __shfl_xor(m, off, 32));
    const float e = expf(v - m);
    float ssum = e;
#pragma unroll
    for (int off = 16; off; off >>= 1) ssum += __shfl_xor(ssum, off, 32);
    sc[tid] = e / ssum;
  }
  __syncthreads();
  float sad = 0.f;
  for (int k2 = 0; k2 < 32; ++k2) sad += sc[k2] * sm[k2 * 129 + tid];
  sa[tid] = sad;
  __syncthreads();
  float o = bv[tid];
  for (int d = 0; d < 128; ++d) o += sa[d] * wvT[d * 128 + tid];
  atten[n * 128 + tid] = o + 0.1f * ego[n * 128 + tid];
}

// ------------------------------------------------------- fusion -------------
__global__ __launch_bounds__(128) void k_fuse1(const float* __restrict__ allemb,
                                               const float* __restrict__ atten,
                                               const float* __restrict__ fw,
                                               const float* __restrict__ fb,
                                               float* __restrict__ z1,
                                               float* __restrict__ z2,
                                               float* __restrict__ cs1,
                                               float* __restrict__ cs2) {
  __shared__ float fwT[128 * 129];
  __shared__ float xr[128], ar[128];
  const int tid = threadIdx.x;
  for (int it = 0; it < 128; ++it) fwT[tid * 129 + it] = fw[it * 128 + tid];
  const float fbj = fb[tid];
  float ls1 = 0.f, ls2 = 0.f;
  const int r0 = blockIdx.x * 64;
  for (int rr = 0; rr < 64; ++rr) {
    const int r = r0 + rr;
    __syncthreads();
    xr[tid] = allemb[r * 128 + tid];
    ar[tid] = atten[r * 128 + tid];
    __syncthreads();
    float a1 = fbj, a2 = fbj;
    for (int d = 0; d < 128; ++d) {
      const float wgt = fwT[d * 129 + tid];
      a1 += xr[d] * wgt;
      a2 += ar[d] * wgt;
    }
    const float t1 = tanhf(a1), t2 = tanhf(a2);
    z1[r * 128 + tid] = t1;
    z2[r * 128 + tid] = t2;
    ls1 += expf(t1 - 1.0f);
    ls2 += expf(t2 - 1.0f);
  }
  atomicAdd(&cs1[tid], ls1);
  atomicAdd(&cs2[tid], ls2);
}

__global__ void k_fuse2(const float* __restrict__ allemb, const float* __restrict__ atten,
                        const float* __restrict__ z1, const float* __restrict__ z2,
                        const float* __restrict__ cs1, const float* __restrict__ cs2,
                        float* __restrict__ fusion) {
  const int i = blockIdx.x * 256 + threadIdx.x;
  const int j = i & 127;
  const float a1 = expf(z1[i] - 1.0f) / cs1[j];
  const float a2 = expf(z2[i] - 1.0f) / cs2[j];
  fusion[i] = a1 * allemb[i] + a2 * atten[i];
}

// ---------------------------------------------------------------- launch ----
extern "C" void kernel_launch(void* const* d_in, const int* in_sizes, int n_in,
                              void* d_out, int out_size, void* d_ws, size_t ws_size,
                              hipStream_t stream) {
  (void)in_sizes; (void)n_in; (void)out_size; (void)ws_size;
  const float* user = (const float*)d_in[0];
  const float* item = (const float*)d_in[1];
  const int* adj_rows = (const int*)d_in[2];
  const int* adj_cols = (const int*)d_in[3];
  const float* adj_vals = (const float*)d_in[4];
  const float* wq = (const float*)d_in[5];
  const float* bq = (const float*)d_in[6];
  const float* wk = (const float*)d_in[7];
  const float* wv = (const float*)d_in[9];
  const float* bv = (const float*)d_in[10];
  const float* fw = (const float*)d_in[11];
  const float* fb = (const float*)d_in[12];

  float* out = (float*)d_out;
  float* allemb = out;                    // [N,D]
  float* atten = out + (size_t)N_ * D_;   // [N,D]
  float* fusion = out + (size_t)2 * N_ * D_;

  char* ws = (char*)d_ws;
  size_t off = 0;
  auto alloc = [&](size_t bytes) { char* p = ws + off; off += (bytes + 255) & ~(size_t)255; return p; };
  float* ego_a = (float*)alloc((size_t)N_ * D_ * 4);
  float* ego_b = (float*)alloc((size_t)N_ * D_ * 4);
  float* qkbuf = (float*)alloc((size_t)N_ * D_ * 4);
  u16* Gh = (u16*)alloc((size_t)N_ * D_ * 2);
  u16* Gl = (u16*)alloc((size_t)N_ * D_ * 2);
  u16* XTh = (u16*)alloc((size_t)N_ * D_ * 2);
  u16* XTl = (u16*)alloc((size_t)N_ * D_ * 2);
  int2* gbuf = (int2*)alloc((size_t)N_ * CAP_ * 8);  // (col,val) pairs (aliased by z1)
  float* z1 = (float*)gbuf;                          // lifetimes disjoint
  float* z2 = (float*)alloc((size_t)N_ * D_ * 4);
  int* topk_idx = (int*)alloc((size_t)N_ * 32 * 4);
  int* ccol = (int*)alloc((size_t)E_ * 4);
  float* cval = (float*)alloc((size_t)E_ * 4);
  int* cnt = (int*)alloc((size_t)N_ * 4);
  int* row_ptr = (int*)alloc((size_t)(N_ + 1) * 4);
  int* cursor = (int*)alloc((size_t)N_ * 4);
  float* M = (float*)alloc(128 * 128 * 4);
  float* bqk = (float*)alloc(128 * 4);
  float* wvT = (float*)alloc(128 * 128 * 4);
  float* cs1 = (float*)alloc(128 * 4);
  float* cs2 = (float*)alloc(128 * 4);
  float* C2 = (float*)alloc(128 * 128 * 4);
  float* svec = (float*)alloc(128 * 4);
  float* tau = (float*)alloc((size_t)N_ * 4);
  int* gcount = (int*)alloc((size_t)N_ * 4);
  int* failq = (int*)alloc(64 * 4);
  int* failn = (int*)alloc(4);
  double* fsim = (double*)alloc((size_t)64 * N_ * 8);

  k_init<<<64, 256, 0, stream>>>(wq, wk, bq, wv, M, bqk, wvT, cnt, cs1, cs2, C2, svec, gcount, failn);
  k_concat<<<8192, 256, 0, stream>>>(user, item, ego_a);
  k_hist<<<2048, 256, 0, stream>>>(adj_rows, cnt);
  k_scan<<<1, 1024, 0, stream>>>(cnt, row_ptr, cursor);
  k_scatter<<<2048, 256, 0, stream>>>(adj_rows, adj_cols, adj_vals, cursor, ccol, cval);

  k_spmm<<<N_, 128, 0, stream>>>(ego_a, ego_b, allemb, row_ptr, ccol, cval, 1);
  k_spmm<<<N_, 128, 0, stream>>>(ego_b, ego_a, allemb, row_ptr, ccol, cval, 0);
  k_spmm<<<N_, 128, 0, stream>>>(ego_a, ego_b, allemb, row_ptr, ccol, cval, 0);
  // ego3 = ego_b
  k_div3<<<8192, 256, 0, stream>>>(allemb);

  k_split_t<<<256, 256, 0, stream>>>(ego_b, Gh, Gl, XTh, XTl, svec);
  k_c2mfma<<<32, 256, 0, stream>>>(XTh, XTl, C2);
  k_tau<<<N_, 128, 0, stream>>>(ego_b, C2, svec, tau);

  k_qk<<<512, 128, 0, stream>>>(ego_b, M, bqk, qkbuf);
  k_simmfma<<<2048, 256, 0, stream>>>(Gh, Gl, tau, gcount, gbuf);   // dense, 2-phase dbuf
  k_check<<<64, 256, 0, stream>>>(gcount, failq, failn);
  k_refine<<<4096, 256, 0, stream>>>(gcount, gbuf, topk_idx);
  k_fallback<<<64, 256, 0, stream>>>(ego_b, failq, failn, fsim, topk_idx);
  k_attn<<<N_, 128, 0, stream>>>(ego_b, qkbuf, topk_idx, wvT, bv, atten);

  k_fuse1<<<256, 128, 0, stream>>>(allemb, atten, fw, fb, z1, z2, cs1, cs2);
  k_fuse2<<<8192, 256, 0, stream>>>(allemb, atten, z1, z2, cs1, cs2, fusion);
}

// Round 4
// 997.715 us; speedup vs baseline: 1.3308x; 1.1284x over previous
//
#include <hip/hip_runtime.h>
#include <math.h>

#define U_ 8192
#define I_ 8192
#define D_ 128
#define E_ 524288
#define N_ 16384
#define K_ 32
#define CAP_ 512

typedef unsigned short u16;
typedef unsigned int u32;
typedef unsigned long long u64;
typedef __attribute__((ext_vector_type(8))) short bf16x8;
typedef __attribute__((ext_vector_type(4))) float f32x4;

// ---------------------------------------------------------------- init ------
__global__ void k_init(const float* __restrict__ wq, const float* __restrict__ wk,
                       const float* __restrict__ bq, const float* __restrict__ wv,
                       float* __restrict__ M, float* __restrict__ bqk,
                       float* __restrict__ wvT,
                       int* __restrict__ cnt, float* __restrict__ cs1,
                       float* __restrict__ cs2, float* __restrict__ C2,
                       float* __restrict__ svec, int* __restrict__ gcount,
                       int* __restrict__ failn) {
  const int tid = blockIdx.x * 256 + threadIdx.x;   // 64 blocks -> 16384 threads
  cnt[tid] = 0;
  gcount[tid] = 0;
  C2[tid] = 0.f;
  if (tid < 128) { cs1[tid] = 0.f; cs2[tid] = 0.f; svec[tid] = 0.f; }
  if (tid == 0) *failn = 0;
  // M[i][j] = sum_l wq[l,i]*wk[l,j]  (wq^T wk)
  const int i = tid >> 7, j = tid & 127;
  float s = 0.f;
  for (int l = 0; l < 128; ++l) s += wq[l * 128 + i] * wk[l * 128 + j];
  M[tid] = s;
  wvT[i * 128 + j] = wv[j * 128 + i];
  if (tid < 128) {
    float s2 = 0.f;
    for (int l = 0; l < 128; ++l) s2 += bq[l] * wk[l * 128 + tid];
    bqk[tid] = s2;
  }
}

__global__ void k_concat(const float* __restrict__ user, const float* __restrict__ item,
                         float* __restrict__ ego) {
  const int i = blockIdx.x * 256 + threadIdx.x;     // 8192 blocks, exact
  ego[i] = (i < U_ * D_) ? user[i] : item[i - U_ * D_];
}

// ---------------------------------------------------------------- CSR -------
__global__ void k_hist(const int* __restrict__ rows, int* __restrict__ cnt) {
  const int e = blockIdx.x * 256 + threadIdx.x;     // 2048 blocks, exact
  atomicAdd(&cnt[rows[e]], 1);
}

// wave-scan rewrite: shfl_up intra-wave + 16-partial scan; 4 barriers/chunk
// instead of the Hillis-Steele 20 (this kernel is a single-block serial
// stage on the critical path).
__global__ void k_scan(const int* __restrict__ cnt, int* __restrict__ row_ptr,
                       int* __restrict__ cursor) {
  __shared__ int wsum[16];
  __shared__ int carry_s;
  const int t = threadIdx.x;                 // 1024 threads
  const int lane = t & 63, wid = t >> 6;
  if (t == 0) carry_s = 0;
  __syncthreads();
  for (int c = 0; c < N_ / 1024; ++c) {
    const int x = cnt[c * 1024 + t];
    int incl = x;
#pragma unroll
    for (int off = 1; off < 64; off <<= 1) {
      const int v = __shfl_up(incl, off, 64);
      if (lane >= off) incl += v;
    }
    if (lane == 63) wsum[wid] = incl;
    __syncthreads();
    if (wid == 0) {
      int s = (lane < 16) ? wsum[lane] : 0;
#pragma unroll
      for (int off = 1; off < 16; off <<= 1) {
        const int v = __shfl_up(s, off, 64);
        if (lane >= off) s += v;
      }
      if (lane < 16) wsum[lane] = s;
    }
    __syncthreads();
    const int carry = carry_s;
    const int wbase = wid ? wsum[wid - 1] : 0;
    const int excl = carry + wbase + incl - x;
    row_ptr[c * 1024 + t] = excl;
    cursor[c * 1024 + t] = excl;
    __syncthreads();
    if (t == 1023) carry_s += wsum[15];
    __syncthreads();
  }
  if (t == 0) row_ptr[N_] = carry_s;
}

__global__ void k_scatter(const int* __restrict__ rows, const int* __restrict__ cols,
                          const float* __restrict__ vals, int* __restrict__ cursor,
                          int* __restrict__ ccol, float* __restrict__ cval) {
  const int e = blockIdx.x * 256 + threadIdx.x;
  const int r = rows[e];
  const int p = atomicAdd(&cursor[r], 1);
  ccol[p] = cols[e];
  cval[p] = vals[e];
}

// ---------------------------------------------------------------- SpMM ------
__global__ __launch_bounds__(128) void k_spmm(const float* __restrict__ x,
                                              float* __restrict__ y,
                                              float* __restrict__ sum,
                                              const int* __restrict__ row_ptr,
                                              const int* __restrict__ ccol,
                                              const float* __restrict__ cval,
                                              const int first) {
  const int r = blockIdx.x, d = threadIdx.x;
  const int b = row_ptr[r], e = row_ptr[r + 1];
  double acc = 0.0;
  for (int i = b; i < e; ++i)
    acc += (double)cval[i] * (double)x[ccol[i] * 128 + d];
  const float f = (float)acc;
  y[r * 128 + d] = f;
  if (first) sum[r * 128 + d] = f; else sum[r * 128 + d] += f;
}

__global__ void k_div3(float* __restrict__ a) {
  const int i = blockIdx.x * 256 + threadIdx.x;
  a[i] = a[i] / 3.0f;
}

// ------------------------------------------------- split + transpose --------
__global__ __launch_bounds__(256) void k_split_t(const float* __restrict__ x,
                                                 u16* __restrict__ Gh, u16* __restrict__ Gl,
                                                 u16* __restrict__ XTh, u16* __restrict__ XTl,
                                                 float* __restrict__ svec) {
  __shared__ u16 lh[128 * 66];
  __shared__ u16 ll[128 * 66];
  const int tid = threadIdx.x;
  const int r0 = blockIdx.x * 64;
  float colsum = 0.f;
  for (int s = 0; s < 32; ++s) {
    const int idx = tid + s * 256;
    const int r = idx >> 7, d = idx & 127;
    const float v = x[(r0 + r) * 128 + d];
    colsum += v;
    unsigned int u = __float_as_uint(v);
    u += 0x7fffu + ((u >> 16) & 1u);
    const u16 h = (u16)(u >> 16);
    const float hf = __uint_as_float(((unsigned int)h) << 16);
    const float l = v - hf;
    unsigned int u2 = __float_as_uint(l);
    u2 += 0x7fffu + ((u2 >> 16) & 1u);
    const u16 lo = (u16)(u2 >> 16);
    Gh[(r0 + r) * 128 + d] = h;
    Gl[(r0 + r) * 128 + d] = lo;
    lh[d * 66 + r] = h;
    ll[d * 66 + r] = lo;
  }
  atomicAdd(&svec[tid & 127], colsum);
  __syncthreads();
  for (int s = 0; s < 32; ++s) {
    const int idx = tid + s * 256;
    const int d = idx >> 6, rr = idx & 63;
    XTh[d * 16384 + r0 + rr] = lh[d * 66 + rr];
    XTl[d * 16384 + r0 + rr] = ll[d * 66 + rr];
  }
}

// ---------------------------------------------------------------- C2 --------
__global__ __launch_bounds__(256) void k_c2mfma(const u16* __restrict__ XTh,
                                                const u16* __restrict__ XTl,
                                                float* __restrict__ C2) {
  const int tid = threadIdx.x, w = tid >> 6, lane = tid & 63;
  const int n16 = lane & 15, kq = lane >> 4;
  const int c0 = blockIdx.x * 512;
  f32x4 acc[2][8];
#pragma unroll
  for (int a = 0; a < 2; ++a)
#pragma unroll
    for (int b = 0; b < 8; ++b) acc[a][b] = (f32x4){0.f, 0.f, 0.f, 0.f};
  for (int ks = 0; ks < 16; ++ks) {
    const int c = c0 + ks * 32 + kq * 8;
    bf16x8 Fh[8], Fl[8];
#pragma unroll
    for (int g = 0; g < 8; ++g) {
      const int base = (g * 16 + n16) * 16384 + c;
      Fh[g] = *(const bf16x8*)&XTh[base];
      Fl[g] = *(const bf16x8*)&XTl[base];
    }
#pragma unroll
    for (int a = 0; a < 2; ++a) {
      const int tr = w * 2 + a;
#pragma unroll
      for (int b = 0; b < 8; ++b) {
        acc[a][b] = __builtin_amdgcn_mfma_f32_16x16x32_bf16(Fl[tr], Fh[b], acc[a][b], 0, 0, 0);
        acc[a][b] = __builtin_amdgcn_mfma_f32_16x16x32_bf16(Fh[tr], Fl[b], acc[a][b], 0, 0, 0);
        acc[a][b] = __builtin_amdgcn_mfma_f32_16x16x32_bf16(Fh[tr], Fh[b], acc[a][b], 0, 0, 0);
      }
    }
  }
#pragma unroll
  for (int a = 0; a < 2; ++a) {
    const int tr = w * 2 + a;
#pragma unroll
    for (int b = 0; b < 8; ++b)
#pragma unroll
      for (int i = 0; i < 4; ++i)
        atomicAdd(&C2[(tr * 16 + kq * 4 + i) * 128 + b * 16 + n16], acc[a][b][i]);
  }
}

// tau_r = mean_r + 2.55 * sigma_r. Containment is STRUCTURAL: count>=36
// guarantees the top-32 (by our scores) all exceed tau; tau only trades
// candidate volume vs fallback frequency.
__global__ __launch_bounds__(128) void k_tau(const float* __restrict__ x,
                                             const float* __restrict__ C2,
                                             const float* __restrict__ svec,
                                             float* __restrict__ tau) {
  __shared__ float xs[128];
  __shared__ double red[128];
  const int n = blockIdx.x, tid = threadIdx.x;
  xs[tid] = x[n * 128 + tid];
  __syncthreads();
  double y = 0.0;
  for (int k2 = 0; k2 < 128; ++k2) y += (double)xs[k2] * (double)C2[k2 * 128 + tid];
  red[tid] = (double)xs[tid] * y;
  __syncthreads();
  for (int s = 64; s; s >>= 1) { if (tid < s) red[tid] += red[tid + s]; __syncthreads(); }
  const double exy = red[0] / 16384.0;
  __syncthreads();
  red[tid] = (double)xs[tid] * (double)svec[tid];
  __syncthreads();
  for (int s = 64; s; s >>= 1) { if (tid < s) red[tid] += red[tid + s]; __syncthreads(); }
  if (tid == 0) {
    const double m = red[0] / 16384.0;
    double var = exy - m * m;
    if (var < 0.0) var = 0.0;
    tau[n] = (float)(m + 2.55 * sqrt(var));
  }
}

// ---------------------------------------------------------------- qk --------
__global__ __launch_bounds__(128) void k_qk(const float* __restrict__ ego,
                                            const float* __restrict__ M,
                                            const float* __restrict__ bqk,
                                            float* __restrict__ qkout) {
  __shared__ float Ml[128 * 128];
  __shared__ float xr[128];
  const int tid = threadIdx.x;
  for (int e = tid; e < 16384; e += 128) Ml[e] = M[e];
  const float bj = bqk[tid];
  for (int r = blockIdx.x; r < N_; r += gridDim.x) {
    __syncthreads();
    xr[tid] = ego[r * 128 + tid];
    __syncthreads();
    float a = bj;
    for (int d = 0; d < 128; ++d) a += xr[d] * Ml[d * 128 + tid];
    qkout[r * 128 + tid] = a;
  }
}

// ------------------------------------------------------- sim via MFMA -------
// Round-4: EXACT round-0 compute structure (best measured: 208 us) -- 16KB
// single-buffer LDS, 2 barriers/st, reg-staged A-tile, 136-stride layout.
// The change: the epilogue's 1.5M device-scope atomicAdd(gcount) RMWs
// (whose cross-XCD line-bouncing explains ~90 of the 101 MB WRITE_SIZE and
// the ~30% unattributed stall) are replaced by LDS-local counters.  Each
// (row,strip) pair is owned by exactly ONE block, so candidates go to the
// per-strip segment gbuf[row*512 + strip*32 + pos] with pos from an LDS
// atomic; one 128-entry count store per block at the end.  Candidate SET
// and (val desc, col asc) ordering are bit-identical; per-strip overflow
// (>32, P~1e-15) routes to the exact fallback like any other count fail.
__global__ __launch_bounds__(256) void k_simmfma(const u16* __restrict__ Gh,
                                                 const u16* __restrict__ Gl,
                                                 const float* __restrict__ tau,
                                                 int* __restrict__ gstripcnt,
                                                 int2* __restrict__ gbuf) {
  __shared__ u16 lh[64 * 136];
  __shared__ int cnt128[128];
  const int tid = threadIdx.x;
  const int w = tid >> 6, lane = tid & 63;
  const int strip = blockIdx.x & 15, rgrp = blockIdx.x >> 4;
  const int n16 = lane & 15, kq = lane >> 4;

  if (tid < 128) cnt128[tid] = 0;

  const int rowbase = rgrp * 128 + w * 32;
  bf16x8 Bh[2][4], Bl[2][4];
#pragma unroll
  for (int rg = 0; rg < 2; ++rg) {
    const int row = rowbase + rg * 16 + n16;
#pragma unroll
    for (int q = 0; q < 4; ++q) {
      Bh[rg][q] = *(const bf16x8*)&Gh[row * 128 + q * 32 + kq * 8];
      Bl[rg][q] = *(const bf16x8*)&Gl[row * 128 + q * 32 + kq * 8];
    }
  }
  const float tau0 = tau[rowbase + n16];
  const float tau1 = tau[rowbase + 16 + n16];
  const int col0 = strip * 1024;
  const int cst = tid >> 2, seg = tid & 3;

  for (int st = 0; st < 16; ++st) {
    const int cb = col0 + st * 64;
    __syncthreads();
#pragma unroll
    for (int i = 0; i < 4; ++i) {
      *(uint4*)&lh[cst * 136 + seg * 32 + i * 8] =
          *(const uint4*)&Gh[(cb + cst) * 128 + seg * 32 + i * 8];
    }
    __syncthreads();
#pragma unroll
    for (int ct = 0; ct < 4; ++ct) {
      bf16x8 Ah[4];
#pragma unroll
      for (int q = 0; q < 4; ++q)
        Ah[q] = *(const bf16x8*)&lh[(ct * 16 + n16) * 136 + q * 32 + kq * 8];
#pragma unroll
      for (int rg = 0; rg < 2; ++rg) {
        f32x4 p = {0.f, 0.f, 0.f, 0.f};
        f32x4 r = {0.f, 0.f, 0.f, 0.f};
#pragma unroll
        for (int q = 0; q < 4; ++q) {
          p = __builtin_amdgcn_mfma_f32_16x16x32_bf16(Ah[q], Bh[rg][q], p, 0, 0, 0);
          r = __builtin_amdgcn_mfma_f32_16x16x32_bf16(Ah[q], Bl[rg][q], r, 0, 0, 0);
        }
        const float tv = rg ? tau1 : tau0;
        const int lrow = w * 32 + rg * 16 + n16;     // block-local row 0..127
        const int row = rgrp * 128 + lrow;
#pragma unroll
        for (int i = 0; i < 4; ++i) {
          const float v = p[i] + r[i];
          if (v > tv) {
            const int c = cb + ct * 16 + kq * 4 + i;
            const int pos = atomicAdd(&cnt128[lrow], 1);   // LDS atomic
            if (pos < 32)
              gbuf[row * CAP_ + strip * 32 + pos] = make_int2(c, __float_as_int(v));
          }
        }
      }
    }
  }
  __syncthreads();
  if (tid < 128) gstripcnt[(rgrp * 128 + tid) * 16 + strip] = cnt128[tid];
}

// rows whose candidate counts violate {total in [36,CAP_], every strip<=32}
// go to the exact fallback
__global__ void k_check(const int* __restrict__ gstripcnt, int* __restrict__ failq,
                        int* __restrict__ failn) {
  const int n = blockIdx.x * 256 + threadIdx.x;   // 64 blocks
  int total = 0; int over = 0;
#pragma unroll
  for (int s = 0; s < 16; ++s) {
    const int c = gstripcnt[n * 16 + s];
    total += c;
    over |= (c > 32);
  }
  if (total < 36 || total > CAP_ || over) {
    const int s = atomicAdd(failn, 1);
    if (s < 64) failq[s] = n;
  }
}

// Top-32 by stored fp32 sim values via RANK-SCATTER on packed u64 keys:
// key = (sortable_f32 << 32) | (16383 - col)  -> (val desc, col asc) order.
// Candidates are gathered from the 16 per-strip segments (compaction);
// col is recovered from the key's low 32 bits. One wave per row.
__global__ __launch_bounds__(256) void k_refine(const int* __restrict__ gstripcnt,
                                                const int2* __restrict__ gbuf,
                                                int* __restrict__ topk_idx) {
  __shared__ u64 lk[4][CAP_];
  const int tid = threadIdx.x, w = tid >> 6, lane = tid & 63;
  const int n = blockIdx.x * 4 + w;

  const int scn = (lane < 16) ? gstripcnt[n * 16 + lane] : 0;
  int total = 0, over = 0;
#pragma unroll
  for (int s = 0; s < 16; ++s) {
    const int c = __shfl(scn, s, 64);
    total += c;
    over |= (c > 32);
  }
  const int bad = (total < 36 || total > CAP_ || over);
  const int cnt = bad ? 0 : total;

  // compact the 16 segments into lk[w][0..cnt)
  int base = 0;
#pragma unroll
  for (int s = 0; s < 16; ++s) {
    const int c = __shfl(scn, s, 64);
    if (!bad && lane < c) {
      const int2 p = gbuf[n * CAP_ + s * 32 + lane];
      u32 uv = (u32)p.y;
      uv = (uv >> 31) ? ~uv : (uv | 0x80000000u);
      lk[w][base + lane] = ((u64)uv << 32) | (u64)(16383 - p.x);
    }
    base += bad ? 0 : c;
  }
  __syncthreads();

  for (int ci = lane; ci < cnt; ci += 64) {
    const u64 kk = lk[w][ci];
    int r = 0;
#pragma unroll 4
    for (int j = 0; j < cnt; ++j)
      r += (lk[w][j] > kk) ? 1 : 0;
    if (r < 32) topk_idx[n * 32 + r] = 16383 - (int)(u32)(kk & 0xffffffffu);
  }
  if (bad && lane < 32) topk_idx[n * 32 + lane] = 0;  // placeholder; fallback overwrites
}

// exact fp64 full-row top-32 for statistically-failed rows (expected: none)
__global__ __launch_bounds__(256) void k_fallback(const float* __restrict__ x,
                                                  const int* __restrict__ failq,
                                                  const int* __restrict__ failn,
                                                  double* __restrict__ fsim,
                                                  int* __restrict__ topk_idx) {
  const int nf = *failn;
  const int which = blockIdx.x;
  if (which >= nf || which >= 64) return;
  const int row = failq[which];
  __shared__ float xs[128];
  __shared__ double bm[256];
  __shared__ int bc[256];
  const int tid = threadIdx.x;
  if (tid < 128) xs[tid] = x[row * 128 + tid];
  __syncthreads();
  double* fs = fsim + (size_t)which * 16384;
  for (int c = tid; c < 16384; c += 256) {
    const float4* xp = (const float4*)&x[c * 128];
    double a = 0.0;
    for (int d = 0; d < 32; ++d) {
      const float4 v = xp[d];
      a += (double)xs[d * 4 + 0] * (double)v.x + (double)xs[d * 4 + 1] * (double)v.y +
           (double)xs[d * 4 + 2] * (double)v.z + (double)xs[d * 4 + 3] * (double)v.w;
    }
    fs[c] = a;
  }
  __syncthreads();
  for (int r = 0; r < 32; ++r) {
    double m = -1.0e300; int mc = 0;
    for (int c = tid; c < 16384; c += 256) {
      const double v = fs[c];
      if (v > m || (v == m && c < mc)) { m = v; mc = c; }
    }
    bm[tid] = m; bc[tid] = mc;
    __syncthreads();
    for (int s = 128; s; s >>= 1) {
      if (tid < s) {
        if (bm[tid + s] > bm[tid] || (bm[tid + s] == bm[tid] && bc[tid + s] < bc[tid])) {
          bm[tid] = bm[tid + s]; bc[tid] = bc[tid + s];
        }
      }
      __syncthreads();
    }
    if (tid == 0) { topk_idx[row * 32 + r] = bc[0]; fs[bc[0]] = -1.0e300; }
    __syncthreads();
  }
}

// ------------------------------------------------------- attention ----------
__global__ __launch_bounds__(128) void k_attn(const float* __restrict__ ego,
                                              const float* __restrict__ qk,
                                              const int* __restrict__ topk_idx,
                                              const float* __restrict__ wvT,
                                              const float* __restrict__ bv,
                                              float* __restrict__ atten) {
  __shared__ float qv[128];
  __shared__ float sm[32 * 129];
  __shared__ int tki[32];
  __shared__ float sc[32];
  __shared__ float sa[128];
  __shared__ float psum[128];
  const int n = blockIdx.x, tid = threadIdx.x;
  qv[tid] = qk[n * 128 + tid];
  if (tid < 32) tki[tid] = topk_idx[n * 32 + tid] & 16383;
  __syncthreads();
  for (int e = tid; e < 32 * 128; e += 128) {
    const int k2 = e >> 7, d = e & 127;
    sm[k2 * 129 + d] = ego[tki[k2] * 128 + d];
  }
  __syncthreads();
  {
    const int kk = tid & 31, part = tid >> 5;
    float s = 0.f;
    const int d0 = part * 32;
    for (int d = d0; d < d0 + 32; ++d) s += qv[d] * sm[kk * 129 + d];
    psum[tid] = s;
  }
  __syncthreads();
  if (tid < 32) {
    float v = psum[tid] + psum[tid + 32] + psum[tid + 64] + psum[tid + 96];
    v *= (1.0f / 11.313708498984760f);    // 1/sqrt(128)
    float m = v;
#pragma unroll
    for (int off = 16; off; off >>= 1) m = fmaxf(m, __shfl_xor(m, off, 32));
    const float e = expf(v - m);
    float ssum = e;
#pragma unroll
    for (int off = 16; off; off >>= 1) ssum += __shfl_xor(ssum, off, 32);
    sc[tid] = e / ssum;
  }
  __syncthreads();
  float sad = 0.f;
  for (int k2 = 0; k2 < 32; ++k2) sad += sc[k2] * sm[k2 * 129 + tid];
  sa[tid] = sad;
  __syncthreads();
  float o = bv[tid];
  for (int d = 0; d < 128; ++d) o += sa[d] * wvT[d * 128 + tid];
  atten[n * 128 + tid] = o + 0.1f * ego[n * 128 + tid];
}

// ------------------------------------------------------- fusion -------------
__global__ __launch_bounds__(128) void k_fuse1(const float* __restrict__ allemb,
                                               const float* __restrict__ atten,
                                               const float* __restrict__ fw,
                                               const float* __restrict__ fb,
                                               float* __restrict__ z1,
                                               float* __restrict__ z2,
                                               float* __restrict__ cs1,
                                               float* __restrict__ cs2) {
  __shared__ float fwT[128 * 129];
  __shared__ float xr[128], ar[128];
  const int tid = threadIdx.x;
  for (int it = 0; it < 128; ++it) fwT[tid * 129 + it] = fw[it * 128 + tid];
  const float fbj = fb[tid];
  float ls1 = 0.f, ls2 = 0.f;
  const int r0 = blockIdx.x * 64;
  for (int rr = 0; rr < 64; ++rr) {
    const int r = r0 + rr;
    __syncthreads();
    xr[tid] = allemb[r * 128 + tid];
    ar[tid] = atten[r * 128 + tid];
    __syncthreads();
    float a1 = fbj, a2 = fbj;
    for (int d = 0; d < 128; ++d) {
      const float wgt = fwT[d * 129 + tid];
      a1 += xr[d] * wgt;
      a2 += ar[d] * wgt;
    }
    const float t1 = tanhf(a1), t2 = tanhf(a2);
    z1[r * 128 + tid] = t1;
    z2[r * 128 + tid] = t2;
    ls1 += expf(t1 - 1.0f);
    ls2 += expf(t2 - 1.0f);
  }
  atomicAdd(&cs1[tid], ls1);
  atomicAdd(&cs2[tid], ls2);
}

__global__ void k_fuse2(const float* __restrict__ allemb, const float* __restrict__ atten,
                        const float* __restrict__ z1, const float* __restrict__ z2,
                        const float* __restrict__ cs1, const float* __restrict__ cs2,
                        float* __restrict__ fusion) {
  const int i = blockIdx.x * 256 + threadIdx.x;
  const int j = i & 127;
  const float a1 = expf(z1[i] - 1.0f) / cs1[j];
  const float a2 = expf(z2[i] - 1.0f) / cs2[j];
  fusion[i] = a1 * allemb[i] + a2 * atten[i];
}

// ---------------------------------------------------------------- launch ----
extern "C" void kernel_launch(void* const* d_in, const int* in_sizes, int n_in,
                              void* d_out, int out_size, void* d_ws, size_t ws_size,
                              hipStream_t stream) {
  (void)in_sizes; (void)n_in; (void)out_size; (void)ws_size;
  const float* user = (const float*)d_in[0];
  const float* item = (const float*)d_in[1];
  const int* adj_rows = (const int*)d_in[2];
  const int* adj_cols = (const int*)d_in[3];
  const float* adj_vals = (const float*)d_in[4];
  const float* wq = (const float*)d_in[5];
  const float* bq = (const float*)d_in[6];
  const float* wk = (const float*)d_in[7];
  const float* wv = (const float*)d_in[9];
  const float* bv = (const float*)d_in[10];
  const float* fw = (const float*)d_in[11];
  const float* fb = (const float*)d_in[12];

  float* out = (float*)d_out;
  float* allemb = out;                    // [N,D]
  float* atten = out + (size_t)N_ * D_;   // [N,D]
  float* fusion = out + (size_t)2 * N_ * D_;

  char* ws = (char*)d_ws;
  size_t off = 0;
  auto alloc = [&](size_t bytes) { char* p = ws + off; off += (bytes + 255) & ~(size_t)255; return p; };
  float* ego_a = (float*)alloc((size_t)N_ * D_ * 4);
  float* ego_b = (float*)alloc((size_t)N_ * D_ * 4);
  float* qkbuf = (float*)alloc((size_t)N_ * D_ * 4);
  u16* Gh = (u16*)alloc((size_t)N_ * D_ * 2);
  u16* Gl = (u16*)alloc((size_t)N_ * D_ * 2);
  u16* XTh = (u16*)alloc((size_t)N_ * D_ * 2);
  u16* XTl = (u16*)alloc((size_t)N_ * D_ * 2);
  int2* gbuf = (int2*)alloc((size_t)N_ * CAP_ * 8);  // (col,val) pairs (aliased by z1)
  float* z1 = (float*)gbuf;                          // lifetimes disjoint
  float* z2 = (float*)alloc((size_t)N_ * D_ * 4);
  int* topk_idx = (int*)alloc((size_t)N_ * 32 * 4);
  int* ccol = (int*)alloc((size_t)E_ * 4);
  float* cval = (float*)alloc((size_t)E_ * 4);
  int* cnt = (int*)alloc((size_t)N_ * 4);
  int* row_ptr = (int*)alloc((size_t)(N_ + 1) * 4);
  int* cursor = (int*)alloc((size_t)N_ * 4);
  float* M = (float*)alloc(128 * 128 * 4);
  float* bqk = (float*)alloc(128 * 4);
  float* wvT = (float*)alloc(128 * 128 * 4);
  float* cs1 = (float*)alloc(128 * 4);
  float* cs2 = (float*)alloc(128 * 4);
  float* C2 = (float*)alloc(128 * 128 * 4);
  float* svec = (float*)alloc(128 * 4);
  float* tau = (float*)alloc((size_t)N_ * 4);
  int* gcount = (int*)alloc((size_t)N_ * 4);          // legacy (unused by hot path)
  int* gstripcnt = (int*)alloc((size_t)N_ * 16 * 4);  // per (row,strip) counts
  int* failq = (int*)alloc(64 * 4);
  int* failn = (int*)alloc(4);
  double* fsim = (double*)alloc((size_t)64 * N_ * 8);

  k_init<<<64, 256, 0, stream>>>(wq, wk, bq, wv, M, bqk, wvT, cnt, cs1, cs2, C2, svec, gcount, failn);
  k_concat<<<8192, 256, 0, stream>>>(user, item, ego_a);
  k_hist<<<2048, 256, 0, stream>>>(adj_rows, cnt);
  k_scan<<<1, 1024, 0, stream>>>(cnt, row_ptr, cursor);
  k_scatter<<<2048, 256, 0, stream>>>(adj_rows, adj_cols, adj_vals, cursor, ccol, cval);

  k_spmm<<<N_, 128, 0, stream>>>(ego_a, ego_b, allemb, row_ptr, ccol, cval, 1);
  k_spmm<<<N_, 128, 0, stream>>>(ego_b, ego_a, allemb, row_ptr, ccol, cval, 0);
  k_spmm<<<N_, 128, 0, stream>>>(ego_a, ego_b, allemb, row_ptr, ccol, cval, 0);
  // ego3 = ego_b
  k_div3<<<8192, 256, 0, stream>>>(allemb);

  k_split_t<<<256, 256, 0, stream>>>(ego_b, Gh, Gl, XTh, XTl, svec);
  k_c2mfma<<<32, 256, 0, stream>>>(XTh, XTl, C2);
  k_tau<<<N_, 128, 0, stream>>>(ego_b, C2, svec, tau);

  k_qk<<<512, 128, 0, stream>>>(ego_b, M, bqk, qkbuf);
  k_simmfma<<<2048, 256, 0, stream>>>(Gh, Gl, tau, gstripcnt, gbuf);
  k_check<<<64, 256, 0, stream>>>(gstripcnt, failq, failn);
  k_refine<<<4096, 256, 0, stream>>>(gstripcnt, gbuf, topk_idx);
  k_fallback<<<64, 256, 0, stream>>>(ego_b, failq, failn, fsim, topk_idx);
  k_attn<<<N_, 128, 0, stream>>>(ego_b, qkbuf, topk_idx, wvT, bv, atten);

  k_fuse1<<<256, 128, 0, stream>>>(allemb, atten, fw, fb, z1, z2, cs1, cs2);
  k_fuse2<<<8192, 256, 0, stream>>>(allemb, atten, z1, z2, cs1, cs2, fusion);
}

// Round 6
// 852.116 us; speedup vs baseline: 1.5582x; 1.1709x over previous
//
#include <hip/hip_runtime.h>
#include <math.h>

#define U_ 8192
#define I_ 8192
#define D_ 128
#define E_ 524288
#define N_ 16384
#define K_ 32
#define CAP_ 512

typedef unsigned short u16;
typedef unsigned int u32;
typedef unsigned long long u64;
typedef __attribute__((ext_vector_type(8))) short bf16x8;
typedef __attribute__((ext_vector_type(4))) float f32x4;

// ---------------------------------------------------------------- init ------
__global__ void k_init(const float* __restrict__ wq, const float* __restrict__ wk,
                       const float* __restrict__ bq, const float* __restrict__ wv,
                       const float* __restrict__ fw,
                       float* __restrict__ M, float* __restrict__ bqk,
                       float* __restrict__ wvT, float* __restrict__ fwdT,
                       int* __restrict__ cnt, float* __restrict__ cs1,
                       float* __restrict__ cs2, float* __restrict__ C2,
                       float* __restrict__ svec, int* __restrict__ gcount,
                       int* __restrict__ failn) {
  const int tid = blockIdx.x * 256 + threadIdx.x;   // 64 blocks -> 16384 threads
  cnt[tid] = 0;
  gcount[tid] = 0;
  C2[tid] = 0.f;
  if (tid < 2048) { cs1[tid] = 0.f; cs2[tid] = 0.f; }   // 16 replicas x 128
  if (tid < 128) svec[tid] = 0.f;
  if (tid == 0) *failn = 0;
  // M[i][j] = sum_l wq[l,i]*wk[l,j]  (wq^T wk)
  const int i = tid >> 7, j = tid & 127;
  float s = 0.f;
  for (int l = 0; l < 128; ++l) s += wq[l * 128 + i] * wk[l * 128 + j];
  M[tid] = s;
  wvT[i * 128 + j] = wv[j * 128 + i];
  fwdT[i * 128 + j] = fw[j * 128 + i];   // fwdT[d][j] = fw[j][d] (d-major)
  if (tid < 128) {
    float s2 = 0.f;
    for (int l = 0; l < 128; ++l) s2 += bq[l] * wk[l * 128 + tid];
    bqk[tid] = s2;
  }
}

__global__ void k_concat(const float* __restrict__ user, const float* __restrict__ item,
                         float* __restrict__ ego) {
  const int i = blockIdx.x * 256 + threadIdx.x;     // 8192 blocks, exact
  ego[i] = (i < U_ * D_) ? user[i] : item[i - U_ * D_];
}

// ---------------------------------------------------------------- CSR -------
__global__ void k_hist(const int* __restrict__ rows, int* __restrict__ cnt) {
  const int e = blockIdx.x * 256 + threadIdx.x;     // 2048 blocks, exact
  atomicAdd(&cnt[rows[e]], 1);
}

// wave-scan: shfl_up intra-wave + 16-partial scan; 4 barriers/chunk.
__global__ void k_scan(const int* __restrict__ cnt, int* __restrict__ row_ptr,
                       int* __restrict__ cursor) {
  __shared__ int wsum[16];
  __shared__ int carry_s;
  const int t = threadIdx.x;                 // 1024 threads
  const int lane = t & 63, wid = t >> 6;
  if (t == 0) carry_s = 0;
  __syncthreads();
  for (int c = 0; c < N_ / 1024; ++c) {
    const int x = cnt[c * 1024 + t];
    int incl = x;
#pragma unroll
    for (int off = 1; off < 64; off <<= 1) {
      const int v = __shfl_up(incl, off, 64);
      if (lane >= off) incl += v;
    }
    if (lane == 63) wsum[wid] = incl;
    __syncthreads();
    if (wid == 0) {
      int s = (lane < 16) ? wsum[lane] : 0;
#pragma unroll
      for (int off = 1; off < 16; off <<= 1) {
        const int v = __shfl_up(s, off, 64);
        if (lane >= off) s += v;
      }
      if (lane < 16) wsum[lane] = s;
    }
    __syncthreads();
    const int carry = carry_s;
    const int wbase = wid ? wsum[wid - 1] : 0;
    const int excl = carry + wbase + incl - x;
    row_ptr[c * 1024 + t] = excl;
    cursor[c * 1024 + t] = excl;
    __syncthreads();
    if (t == 1023) carry_s += wsum[15];
    __syncthreads();
  }
  if (t == 0) row_ptr[N_] = carry_s;
}

__global__ void k_scatter(const int* __restrict__ rows, const int* __restrict__ cols,
                          const float* __restrict__ vals, int* __restrict__ cursor,
                          int* __restrict__ ccol, float* __restrict__ cval) {
  const int e = blockIdx.x * 256 + threadIdx.x;
  const int r = rows[e];
  const int p = atomicAdd(&cursor[r], 1);
  ccol[p] = cols[e];
  cval[p] = vals[e];
}

// ---------------------------------------------------------------- SpMM ------
__global__ __launch_bounds__(128) void k_spmm(const float* __restrict__ x,
                                              float* __restrict__ y,
                                              float* __restrict__ sum,
                                              const int* __restrict__ row_ptr,
                                              const int* __restrict__ ccol,
                                              const float* __restrict__ cval,
                                              const int first) {
  const int r = blockIdx.x, d = threadIdx.x;
  const int b = row_ptr[r], e = row_ptr[r + 1];
  double acc = 0.0;
  for (int i = b; i < e; ++i)
    acc += (double)cval[i] * (double)x[ccol[i] * 128 + d];
  const float f = (float)acc;
  y[r * 128 + d] = f;
  if (first) sum[r * 128 + d] = f; else sum[r * 128 + d] += f;
}

__global__ void k_div3(float* __restrict__ a) {
  const int i = blockIdx.x * 256 + threadIdx.x;
  a[i] = a[i] / 3.0f;
}

// ------------------------------------------------- split + transpose --------
__global__ __launch_bounds__(256) void k_split_t(const float* __restrict__ x,
                                                 u16* __restrict__ Gh, u16* __restrict__ Gl,
                                                 u16* __restrict__ XTh, u16* __restrict__ XTl,
                                                 float* __restrict__ svec) {
  __shared__ u16 lh[128 * 66];
  __shared__ u16 ll[128 * 66];
  const int tid = threadIdx.x;
  const int r0 = blockIdx.x * 64;
  float colsum = 0.f;
  for (int s = 0; s < 32; ++s) {
    const int idx = tid + s * 256;
    const int r = idx >> 7, d = idx & 127;
    const float v = x[(r0 + r) * 128 + d];
    colsum += v;
    unsigned int u = __float_as_uint(v);
    u += 0x7fffu + ((u >> 16) & 1u);
    const u16 h = (u16)(u >> 16);
    const float hf = __uint_as_float(((unsigned int)h) << 16);
    const float l = v - hf;
    unsigned int u2 = __float_as_uint(l);
    u2 += 0x7fffu + ((u2 >> 16) & 1u);
    const u16 lo = (u16)(u2 >> 16);
    Gh[(r0 + r) * 128 + d] = h;
    Gl[(r0 + r) * 128 + d] = lo;
    lh[d * 66 + r] = h;
    ll[d * 66 + r] = lo;
  }
  atomicAdd(&svec[tid & 127], colsum);
  __syncthreads();
  for (int s = 0; s < 32; ++s) {
    const int idx = tid + s * 256;
    const int d = idx >> 6, rr = idx & 63;
    XTh[d * 16384 + r0 + rr] = lh[d * 66 + rr];
    XTl[d * 16384 + r0 + rr] = ll[d * 66 + rr];
  }
}

// ---------------------------------------------------------------- C2 --------
__global__ __launch_bounds__(256) void k_c2mfma(const u16* __restrict__ XTh,
                                                const u16* __restrict__ XTl,
                                                float* __restrict__ C2) {
  const int tid = threadIdx.x, w = tid >> 6, lane = tid & 63;
  const int n16 = lane & 15, kq = lane >> 4;
  const int c0 = blockIdx.x * 512;
  f32x4 acc[2][8];
#pragma unroll
  for (int a = 0; a < 2; ++a)
#pragma unroll
    for (int b = 0; b < 8; ++b) acc[a][b] = (f32x4){0.f, 0.f, 0.f, 0.f};
  for (int ks = 0; ks < 16; ++ks) {
    const int c = c0 + ks * 32 + kq * 8;
    bf16x8 Fh[8], Fl[8];
#pragma unroll
    for (int g = 0; g < 8; ++g) {
      const int base = (g * 16 + n16) * 16384 + c;
      Fh[g] = *(const bf16x8*)&XTh[base];
      Fl[g] = *(const bf16x8*)&XTl[base];
    }
#pragma unroll
    for (int a = 0; a < 2; ++a) {
      const int tr = w * 2 + a;
#pragma unroll
      for (int b = 0; b < 8; ++b) {
        acc[a][b] = __builtin_amdgcn_mfma_f32_16x16x32_bf16(Fl[tr], Fh[b], acc[a][b], 0, 0, 0);
        acc[a][b] = __builtin_amdgcn_mfma_f32_16x16x32_bf16(Fh[tr], Fl[b], acc[a][b], 0, 0, 0);
        acc[a][b] = __builtin_amdgcn_mfma_f32_16x16x32_bf16(Fh[tr], Fh[b], acc[a][b], 0, 0, 0);
      }
    }
  }
#pragma unroll
  for (int a = 0; a < 2; ++a) {
    const int tr = w * 2 + a;
#pragma unroll
    for (int b = 0; b < 8; ++b)
#pragma unroll
      for (int i = 0; i < 4; ++i)
        atomicAdd(&C2[(tr * 16 + kq * 4 + i) * 128 + b * 16 + n16], acc[a][b][i]);
  }
}

// tau_r = mean_r + 2.55 * sigma_r. Containment is STRUCTURAL: count>=36
// guarantees the top-32 (by our scores) all exceed tau; tau only trades
// candidate volume vs fallback frequency.
__global__ __launch_bounds__(128) void k_tau(const float* __restrict__ x,
                                             const float* __restrict__ C2,
                                             const float* __restrict__ svec,
                                             float* __restrict__ tau) {
  __shared__ float xs[128];
  __shared__ double red[128];
  const int n = blockIdx.x, tid = threadIdx.x;
  xs[tid] = x[n * 128 + tid];
  __syncthreads();
  double y = 0.0;
  for (int k2 = 0; k2 < 128; ++k2) y += (double)xs[k2] * (double)C2[k2 * 128 + tid];
  red[tid] = (double)xs[tid] * y;
  __syncthreads();
  for (int s = 64; s; s >>= 1) { if (tid < s) red[tid] += red[tid + s]; __syncthreads(); }
  const double exy = red[0] / 16384.0;
  __syncthreads();
  red[tid] = (double)xs[tid] * (double)svec[tid];
  __syncthreads();
  for (int s = 64; s; s >>= 1) { if (tid < s) red[tid] += red[tid + s]; __syncthreads(); }
  if (tid == 0) {
    const double m = red[0] / 16384.0;
    double var = exy - m * m;
    if (var < 0.0) var = 0.0;
    tau[n] = (float)(m + 2.55 * sqrt(var));
  }
}

// ---------------------------------------------------------------- qk --------
// v2: thin-tile matmul, 2048 blocks x 256 threads, 8 rows/block in 4KB LDS.
// Weight access M[d*128+j] is lane-contiguous (coalesced, L1-hot 64KB);
// x broadcast from LDS (same-address across wave -> conflict-free).
// Fixes the round-4 occupancy disease (64KB LDS Ml, 512 blocks -> 12%).
__global__ __launch_bounds__(256) void k_qk(const float* __restrict__ ego,
                                            const float* __restrict__ M,
                                            const float* __restrict__ bqk,
                                            float* __restrict__ qkout) {
  __shared__ float xs[8][128];
  const int tid = threadIdx.x;
  const int r0 = blockIdx.x * 8;
#pragma unroll
  for (int s = 0; s < 4; ++s) {
    const int idx = tid + s * 256;
    xs[idx >> 7][idx & 127] = ego[r0 * 128 + idx];
  }
  __syncthreads();
  const int j = tid & 127, h = tid >> 7;
  const float bj = bqk[j];
  float acc[4];
#pragma unroll
  for (int r = 0; r < 4; ++r) acc[r] = bj;
  for (int d = 0; d < 128; d += 4) {
    const float w0 = M[(d + 0) * 128 + j];
    const float w1 = M[(d + 1) * 128 + j];
    const float w2 = M[(d + 2) * 128 + j];
    const float w3 = M[(d + 3) * 128 + j];
#pragma unroll
    for (int r = 0; r < 4; ++r) {
      const float4 xv = *(const float4*)&xs[h * 4 + r][d];
      acc[r] += xv.x * w0 + xv.y * w1 + xv.z * w2 + xv.w * w3;
    }
  }
#pragma unroll
  for (int r = 0; r < 4; ++r)
    qkout[(r0 + h * 4 + r) * 128 + j] = acc[r];
}

// ------------------------------------------------------- sim via MFMA -------
// Round-4 winner: round-0 compute structure + LDS-local candidate counters
// and per-(row,strip) output segments (no device-scope atomics).
__global__ __launch_bounds__(256) void k_simmfma(const u16* __restrict__ Gh,
                                                 const u16* __restrict__ Gl,
                                                 const float* __restrict__ tau,
                                                 int* __restrict__ gstripcnt,
                                                 int2* __restrict__ gbuf) {
  __shared__ u16 lh[64 * 136];
  __shared__ int cnt128[128];
  const int tid = threadIdx.x;
  const int w = tid >> 6, lane = tid & 63;
  const int strip = blockIdx.x & 15, rgrp = blockIdx.x >> 4;
  const int n16 = lane & 15, kq = lane >> 4;

  if (tid < 128) cnt128[tid] = 0;

  const int rowbase = rgrp * 128 + w * 32;
  bf16x8 Bh[2][4], Bl[2][4];
#pragma unroll
  for (int rg = 0; rg < 2; ++rg) {
    const int row = rowbase + rg * 16 + n16;
#pragma unroll
    for (int q = 0; q < 4; ++q) {
      Bh[rg][q] = *(const bf16x8*)&Gh[row * 128 + q * 32 + kq * 8];
      Bl[rg][q] = *(const bf16x8*)&Gl[row * 128 + q * 32 + kq * 8];
    }
  }
  const float tau0 = tau[rowbase + n16];
  const float tau1 = tau[rowbase + 16 + n16];
  const int col0 = strip * 1024;
  const int cst = tid >> 2, seg = tid & 3;

  for (int st = 0; st < 16; ++st) {
    const int cb = col0 + st * 64;
    __syncthreads();
#pragma unroll
    for (int i = 0; i < 4; ++i) {
      *(uint4*)&lh[cst * 136 + seg * 32 + i * 8] =
          *(const uint4*)&Gh[(cb + cst) * 128 + seg * 32 + i * 8];
    }
    __syncthreads();
#pragma unroll
    for (int ct = 0; ct < 4; ++ct) {
      bf16x8 Ah[4];
#pragma unroll
      for (int q = 0; q < 4; ++q)
        Ah[q] = *(const bf16x8*)&lh[(ct * 16 + n16) * 136 + q * 32 + kq * 8];
#pragma unroll
      for (int rg = 0; rg < 2; ++rg) {
        f32x4 p = {0.f, 0.f, 0.f, 0.f};
        f32x4 r = {0.f, 0.f, 0.f, 0.f};
#pragma unroll
        for (int q = 0; q < 4; ++q) {
          p = __builtin_amdgcn_mfma_f32_16x16x32_bf16(Ah[q], Bh[rg][q], p, 0, 0, 0);
          r = __builtin_amdgcn_mfma_f32_16x16x32_bf16(Ah[q], Bl[rg][q], r, 0, 0, 0);
        }
        const float tv = rg ? tau1 : tau0;
        const int lrow = w * 32 + rg * 16 + n16;     // block-local row 0..127
        const int row = rgrp * 128 + lrow;
#pragma unroll
        for (int i = 0; i < 4; ++i) {
          const float v = p[i] + r[i];
          if (v > tv) {
            const int c = cb + ct * 16 + kq * 4 + i;
            const int pos = atomicAdd(&cnt128[lrow], 1);   // LDS atomic
            if (pos < 32)
              gbuf[row * CAP_ + strip * 32 + pos] = make_int2(c, __float_as_int(v));
          }
        }
      }
    }
  }
  __syncthreads();
  if (tid < 128) gstripcnt[(rgrp * 128 + tid) * 16 + strip] = cnt128[tid];
}

// rows whose candidate counts violate {total in [36,CAP_], every strip<=32}
// go to the exact fallback
__global__ void k_check(const int* __restrict__ gstripcnt, int* __restrict__ failq,
                        int* __restrict__ failn) {
  const int n = blockIdx.x * 256 + threadIdx.x;   // 64 blocks
  int total = 0; int over = 0;
#pragma unroll
  for (int s = 0; s < 16; ++s) {
    const int c = gstripcnt[n * 16 + s];
    total += c;
    over |= (c > 32);
  }
  if (total < 36 || total > CAP_ || over) {
    const int s = atomicAdd(failn, 1);
    if (s < 64) failq[s] = n;
  }
}

// Top-32 by stored fp32 sim values via RANK-SCATTER on packed u64 keys:
// key = (sortable_f32 << 32) | (16383 - col)  -> (val desc, col asc) order.
// Candidates gathered from the 16 per-strip segments; col recovered from
// the key's low 32 bits. One wave per row.
__global__ __launch_bounds__(256) void k_refine(const int* __restrict__ gstripcnt,
                                                const int2* __restrict__ gbuf,
                                                int* __restrict__ topk_idx) {
  __shared__ u64 lk[4][CAP_];
  const int tid = threadIdx.x, w = tid >> 6, lane = tid & 63;
  const int n = blockIdx.x * 4 + w;

  const int scn = (lane < 16) ? gstripcnt[n * 16 + lane] : 0;
  int total = 0, over = 0;
#pragma unroll
  for (int s = 0; s < 16; ++s) {
    const int c = __shfl(scn, s, 64);
    total += c;
    over |= (c > 32);
  }
  const int bad = (total < 36 || total > CAP_ || over);
  const int cnt = bad ? 0 : total;

  // compact the 16 segments into lk[w][0..cnt)
  int base = 0;
#pragma unroll
  for (int s = 0; s < 16; ++s) {
    const int c = __shfl(scn, s, 64);
    if (!bad && lane < c) {
      const int2 p = gbuf[n * CAP_ + s * 32 + lane];
      u32 uv = (u32)p.y;
      uv = (uv >> 31) ? ~uv : (uv | 0x80000000u);
      lk[w][base + lane] = ((u64)uv << 32) | (u64)(16383 - p.x);
    }
    base += bad ? 0 : c;
  }
  __syncthreads();

  for (int ci = lane; ci < cnt; ci += 64) {
    const u64 kk = lk[w][ci];
    int r = 0;
#pragma unroll 4
    for (int j = 0; j < cnt; ++j)
      r += (lk[w][j] > kk) ? 1 : 0;
    if (r < 32) topk_idx[n * 32 + r] = 16383 - (int)(u32)(kk & 0xffffffffu);
  }
  if (bad && lane < 32) topk_idx[n * 32 + lane] = 0;  // placeholder; fallback overwrites
}

// exact fp64 full-row top-32 for statistically-failed rows (expected: none)
__global__ __launch_bounds__(256) void k_fallback(const float* __restrict__ x,
                                                  const int* __restrict__ failq,
                                                  const int* __restrict__ failn,
                                                  double* __restrict__ fsim,
                                                  int* __restrict__ topk_idx) {
  const int nf = *failn;
  const int which = blockIdx.x;
  if (which >= nf || which >= 64) return;
  const int row = failq[which];
  __shared__ float xs[128];
  __shared__ double bm[256];
  __shared__ int bc[256];
  const int tid = threadIdx.x;
  if (tid < 128) xs[tid] = x[row * 128 + tid];
  __syncthreads();
  double* fs = fsim + (size_t)which * 16384;
  for (int c = tid; c < 16384; c += 256) {
    const float4* xp = (const float4*)&x[c * 128];
    double a = 0.0;
    for (int d = 0; d < 32; ++d) {
      const float4 v = xp[d];
      a += (double)xs[d * 4 + 0] * (double)v.x + (double)xs[d * 4 + 1] * (double)v.y +
           (double)xs[d * 4 + 2] * (double)v.z + (double)xs[d * 4 + 3] * (double)v.w;
    }
    fs[c] = a;
  }
  __syncthreads();
  for (int r = 0; r < 32; ++r) {
    double m = -1.0e300; int mc = 0;
    for (int c = tid; c < 16384; c += 256) {
      const double v = fs[c];
      if (v > m || (v == m && c < mc)) { m = v; mc = c; }
    }
    bm[tid] = m; bc[tid] = mc;
    __syncthreads();
    for (int s = 128; s; s >>= 1) {
      if (tid < s) {
        if (bm[tid + s] > bm[tid] || (bm[tid + s] == bm[tid] && bc[tid + s] < bc[tid])) {
          bm[tid] = bm[tid + s]; bc[tid] = bc[tid + s];
        }
      }
      __syncthreads();
    }
    if (tid == 0) { topk_idx[row * 32 + r] = bc[0]; fs[bc[0]] = -1.0e300; }
    __syncthreads();
  }
}

// ------------------------------------------------------- attention ----------
__global__ __launch_bounds__(128) void k_attn(const float* __restrict__ ego,
                                              const float* __restrict__ qk,
                                              const int* __restrict__ topk_idx,
                                              const float* __restrict__ wvT,
                                              const float* __restrict__ bv,
                                              float* __restrict__ atten) {
  __shared__ float qv[128];
  __shared__ float sm[32 * 129];
  __shared__ int tki[32];
  __shared__ float sc[32];
  __shared__ float sa[128];
  __shared__ float psum[128];
  const int n = blockIdx.x, tid = threadIdx.x;
  qv[tid] = qk[n * 128 + tid];
  if (tid < 32) tki[tid] = topk_idx[n * 32 + tid] & 16383;
  __syncthreads();
  for (int e = tid; e < 32 * 128; e += 128) {
    const int k2 = e >> 7, d = e & 127;
    sm[k2 * 129 + d] = ego[tki[k2] * 128 + d];
  }
  __syncthreads();
  {
    const int kk = tid & 31, part = tid >> 5;
    float s = 0.f;
    const int d0 = part * 32;
    for (int d = d0; d < d0 + 32; ++d) s += qv[d] * sm[kk * 129 + d];
    psum[tid] = s;
  }
  __syncthreads();
  if (tid < 32) {
    float v = psum[tid] + psum[tid + 32] + psum[tid + 64] + psum[tid + 96];
    v *= (1.0f / 11.313708498984760f);    // 1/sqrt(128)
    float m = v;
#pragma unroll
    for (int off = 16; off; off >>= 1) m = fmaxf(m, __shfl_xor(m, off, 32));
    const float e = expf(v - m);
    float ssum = e;
#pragma unroll
    for (int off = 16; off; off >>= 1) ssum += __shfl_xor(ssum, off, 32);
    sc[tid] = e / ssum;
  }
  __syncthreads();
  float sad = 0.f;
  for (int k2 = 0; k2 < 32; ++k2) sad += sc[k2] * sm[k2 * 129 + tid];
  sa[tid] = sad;
  __syncthreads();
  float o = bv[tid];
  for (int d = 0; d < 128; ++d) o += sa[d] * wvT[d * 128 + tid];
  atten[n * 128 + tid] = o + 0.1f * ego[n * 128 + tid];
}

// ------------------------------------------------------- fusion -------------
// v2: thin-tile matmul pair, 2048 blocks x 256 threads, 8 rows/block in
// 8KB LDS; weight read d-major via fwdT (lane-contiguous, L1-hot).  Fixes
// the 5.4%-occupancy disease (was: 67KB LDS fwT, 256 blocks -> 1 block x
// 2 waves per CU, 177us for a 7us-of-FLOPs matmul).  cs sums go to 16
// bid-indexed replicas (128 atomics/address) reduced in k_fuse2.
__global__ __launch_bounds__(256) void k_fuse1(const float* __restrict__ allemb,
                                               const float* __restrict__ atten,
                                               const float* __restrict__ fwdT,
                                               const float* __restrict__ fb,
                                               float* __restrict__ z1,
                                               float* __restrict__ z2,
                                               float* __restrict__ cs1,
                                               float* __restrict__ cs2) {
  __shared__ float xs[8][128];
  __shared__ float as[8][128];
  __shared__ float red1[2][128];
  __shared__ float red2[2][128];
  const int tid = threadIdx.x;
  const int r0 = blockIdx.x * 8;
#pragma unroll
  for (int s = 0; s < 4; ++s) {
    const int idx = tid + s * 256;
    const int rr = idx >> 7, d = idx & 127;
    xs[rr][d] = allemb[(r0 + rr) * 128 + d];
    as[rr][d] = atten[(r0 + rr) * 128 + d];
  }
  __syncthreads();
  const int j = tid & 127, h = tid >> 7;
  const float fbj = fb[j];
  float acc1[4], acc2[4];
#pragma unroll
  for (int r = 0; r < 4; ++r) { acc1[r] = fbj; acc2[r] = fbj; }
  for (int d = 0; d < 128; d += 4) {
    const float w0 = fwdT[(d + 0) * 128 + j];
    const float w1 = fwdT[(d + 1) * 128 + j];
    const float w2 = fwdT[(d + 2) * 128 + j];
    const float w3 = fwdT[(d + 3) * 128 + j];
#pragma unroll
    for (int r = 0; r < 4; ++r) {
      const int rr = h * 4 + r;
      const float4 xv = *(const float4*)&xs[rr][d];
      const float4 av = *(const float4*)&as[rr][d];
      acc1[r] += xv.x * w0 + xv.y * w1 + xv.z * w2 + xv.w * w3;
      acc2[r] += av.x * w0 + av.y * w1 + av.z * w2 + av.w * w3;
    }
  }
  float ls1 = 0.f, ls2 = 0.f;
#pragma unroll
  for (int r = 0; r < 4; ++r) {
    const int rr = h * 4 + r;
    const float t1 = tanhf(acc1[r]);
    const float t2 = tanhf(acc2[r]);
    z1[(r0 + rr) * 128 + j] = t1;
    z2[(r0 + rr) * 128 + j] = t2;
    ls1 += expf(t1 - 1.0f);
    ls2 += expf(t2 - 1.0f);
  }
  red1[h][j] = ls1;
  red2[h][j] = ls2;
  __syncthreads();
  if (h == 0) {
    const int rep = blockIdx.x & 15;
    atomicAdd(&cs1[rep * 128 + j], red1[0][j] + red1[1][j]);
    atomicAdd(&cs2[rep * 128 + j], red2[0][j] + red2[1][j]);
  }
}

__global__ void k_fuse2(const float* __restrict__ allemb, const float* __restrict__ atten,
                        const float* __restrict__ z1, const float* __restrict__ z2,
                        const float* __restrict__ cs1, const float* __restrict__ cs2,
                        float* __restrict__ fusion) {
  __shared__ float s1[128], s2[128];
  const int tid = threadIdx.x;
  if (tid < 128) {
    float a = 0.f, b = 0.f;
#pragma unroll
    for (int rep = 0; rep < 16; ++rep) {
      a += cs1[rep * 128 + tid];
      b += cs2[rep * 128 + tid];
    }
    s1[tid] = a; s2[tid] = b;
  }
  __syncthreads();
  const int i = blockIdx.x * 256 + tid;
  const int j = i & 127;
  const float a1 = expf(z1[i] - 1.0f) / s1[j];
  const float a2 = expf(z2[i] - 1.0f) / s2[j];
  fusion[i] = a1 * allemb[i] + a2 * atten[i];
}

// ---------------------------------------------------------------- launch ----
extern "C" void kernel_launch(void* const* d_in, const int* in_sizes, int n_in,
                              void* d_out, int out_size, void* d_ws, size_t ws_size,
                              hipStream_t stream) {
  (void)in_sizes; (void)n_in; (void)out_size; (void)ws_size;
  const float* user = (const float*)d_in[0];
  const float* item = (const float*)d_in[1];
  const int* adj_rows = (const int*)d_in[2];
  const int* adj_cols = (const int*)d_in[3];
  const float* adj_vals = (const float*)d_in[4];
  const float* wq = (const float*)d_in[5];
  const float* bq = (const float*)d_in[6];
  const float* wk = (const float*)d_in[7];
  const float* wv = (const float*)d_in[9];
  const float* bv = (const float*)d_in[10];
  const float* fw = (const float*)d_in[11];
  const float* fb = (const float*)d_in[12];

  float* out = (float*)d_out;
  float* allemb = out;                    // [N,D]
  float* atten = out + (size_t)N_ * D_;   // [N,D]
  float* fusion = out + (size_t)2 * N_ * D_;

  char* ws = (char*)d_ws;
  size_t off = 0;
  auto alloc = [&](size_t bytes) { char* p = ws + off; off += (bytes + 255) & ~(size_t)255; return p; };
  float* ego_a = (float*)alloc((size_t)N_ * D_ * 4);
  float* ego_b = (float*)alloc((size_t)N_ * D_ * 4);
  float* qkbuf = (float*)alloc((size_t)N_ * D_ * 4);
  u16* Gh = (u16*)alloc((size_t)N_ * D_ * 2);
  u16* Gl = (u16*)alloc((size_t)N_ * D_ * 2);
  u16* XTh = (u16*)alloc((size_t)N_ * D_ * 2);
  u16* XTl = (u16*)alloc((size_t)N_ * D_ * 2);
  int2* gbuf = (int2*)alloc((size_t)N_ * CAP_ * 8);  // (col,val) pairs (aliased by z1)
  float* z1 = (float*)gbuf;                          // lifetimes disjoint
  float* z2 = (float*)alloc((size_t)N_ * D_ * 4);
  int* topk_idx = (int*)alloc((size_t)N_ * 32 * 4);
  int* ccol = (int*)alloc((size_t)E_ * 4);
  float* cval = (float*)alloc((size_t)E_ * 4);
  int* cnt = (int*)alloc((size_t)N_ * 4);
  int* row_ptr = (int*)alloc((size_t)(N_ + 1) * 4);
  int* cursor = (int*)alloc((size_t)N_ * 4);
  float* M = (float*)alloc(128 * 128 * 4);
  float* bqk = (float*)alloc(128 * 4);
  float* wvT = (float*)alloc(128 * 128 * 4);
  float* fwdT = (float*)alloc(128 * 128 * 4);
  float* cs1 = (float*)alloc(16 * 128 * 4);           // 16 replicas
  float* cs2 = (float*)alloc(16 * 128 * 4);
  float* C2 = (float*)alloc(128 * 128 * 4);
  float* svec = (float*)alloc(128 * 4);
  float* tau = (float*)alloc((size_t)N_ * 4);
  int* gcount = (int*)alloc((size_t)N_ * 4);          // legacy (unused by hot path)
  int* gstripcnt = (int*)alloc((size_t)N_ * 16 * 4);  // per (row,strip) counts
  int* failq = (int*)alloc(64 * 4);
  int* failn = (int*)alloc(4);
  double* fsim = (double*)alloc((size_t)64 * N_ * 8);

  k_init<<<64, 256, 0, stream>>>(wq, wk, bq, wv, fw, M, bqk, wvT, fwdT, cnt, cs1, cs2, C2, svec, gcount, failn);
  k_concat<<<8192, 256, 0, stream>>>(user, item, ego_a);
  k_hist<<<2048, 256, 0, stream>>>(adj_rows, cnt);
  k_scan<<<1, 1024, 0, stream>>>(cnt, row_ptr, cursor);
  k_scatter<<<2048, 256, 0, stream>>>(adj_rows, adj_cols, adj_vals, cursor, ccol, cval);

  k_spmm<<<N_, 128, 0, stream>>>(ego_a, ego_b, allemb, row_ptr, ccol, cval, 1);
  k_spmm<<<N_, 128, 0, stream>>>(ego_b, ego_a, allemb, row_ptr, ccol, cval, 0);
  k_spmm<<<N_, 128, 0, stream>>>(ego_a, ego_b, allemb, row_ptr, ccol, cval, 0);
  // ego3 = ego_b
  k_div3<<<8192, 256, 0, stream>>>(allemb);

  k_split_t<<<256, 256, 0, stream>>>(ego_b, Gh, Gl, XTh, XTl, svec);
  k_c2mfma<<<32, 256, 0, stream>>>(XTh, XTl, C2);
  k_tau<<<N_, 128, 0, stream>>>(ego_b, C2, svec, tau);

  k_qk<<<2048, 256, 0, stream>>>(ego_b, M, bqk, qkbuf);
  k_simmfma<<<2048, 256, 0, stream>>>(Gh, Gl, tau, gstripcnt, gbuf);
  k_check<<<64, 256, 0, stream>>>(gstripcnt, failq, failn);
  k_refine<<<4096, 256, 0, stream>>>(gstripcnt, gbuf, topk_idx);
  k_fallback<<<64, 256, 0, stream>>>(ego_b, failq, failn, fsim, topk_idx);
  k_attn<<<N_, 128, 0, stream>>>(ego_b, qkbuf, topk_idx, wvT, bv, atten);

  k_fuse1<<<2048, 256, 0, stream>>>(allemb, atten, fwdT, fb, z1, z2, cs1, cs2);
  k_fuse2<<<8192, 256, 0, stream>>>(allemb, atten, z1, z2, cs1, cs2, fusion);
}